// Round 2
// baseline (3421.001 us; speedup 1.0000x reference)
//
#include <hip/hip_runtime.h>
#include <math.h>

#define ACT_LRELU  0
#define ACT_SIGMAP 1
#define ACT_SQUARE 2

static __device__ __forceinline__ float lrelu(float x) { return x >= 0.f ? x : 0.2f * x; }

// -------------------------------------------------------------------------
// Small conv: k=3, pad=1, T=64. Two independent paths fused via blockIdx.z.
// Block: 256 thr = 16 co-quads (ty) x 16 t-quads (tx); tile = 64 co x 64 t.
// -------------------------------------------------------------------------
__global__ void __launch_bounds__(256) conv_small(
    const float* __restrict__ inm, const float* __restrict__ ing,
    const float* __restrict__ Wm, const float* __restrict__ Bm,
    const float* __restrict__ Wg, const float* __restrict__ Bg,
    float* __restrict__ outm, float* __restrict__ outg,
    int Cin, int Cout, int actm, int actg)
{
  const int p = blockIdx.z;
  const float* in = p ? ing : inm;
  const float* W  = p ? Wg  : Wm;
  const float* Bs = p ? Bg  : Bm;
  float* out      = p ? outg : outm;
  const int act   = p ? actg : actm;

  const int coBase = blockIdx.x * 64;
  const int b   = blockIdx.y;
  const int tid = threadIdx.x;
  const int tx  = tid & 15;   // t quad
  const int ty  = tid >> 4;   // co quad

  __shared__ __align__(16) float inS[64][68];   // [ci][u], u = t_in + 1, u in [0,66)
  __shared__ __align__(16) float wS[64][192];   // [ci][co_l*3 + k]

  float acc[4][4] = {};

  for (int ci0 = 0; ci0 < Cin; ci0 += 64) {
    for (int e = tid; e < 64 * 66; e += 256) {
      int ci = e / 66, u = e - ci * 66;
      int tin = u - 1;
      float v = 0.f;
      if (tin >= 0 && tin < 64) v = in[(size_t)(b * Cin + ci0 + ci) * 64 + tin];
      inS[ci][u] = v;
    }
    for (int e = tid; e < 64 * 64; e += 256) {
      int col = e >> 6, ci = e & 63;
      const float* wp = W + ((size_t)(coBase + col) * Cin + (ci0 + ci)) * 3;
      wS[ci][col * 3 + 0] = wp[0];
      wS[ci][col * 3 + 1] = wp[1];
      wS[ci][col * 3 + 2] = wp[2];
    }
    __syncthreads();
    for (int ci = 0; ci < 64; ++ci) {
      const float4* ip = reinterpret_cast<const float4*>(&inS[ci][tx * 4]);
      float4 i03 = ip[0];
      float2 i45 = *reinterpret_cast<const float2*>(&inS[ci][tx * 4 + 4]);
      float iv[6] = {i03.x, i03.y, i03.z, i03.w, i45.x, i45.y};
      const float4* wp4 = reinterpret_cast<const float4*>(&wS[ci][ty * 12]);
      float4 wa = wp4[0], wb = wp4[1], wc = wp4[2];
      float w[12] = {wa.x, wa.y, wa.z, wa.w, wb.x, wb.y, wb.z, wb.w, wc.x, wc.y, wc.z, wc.w};
#pragma unroll
      for (int cc = 0; cc < 4; ++cc)
#pragma unroll
        for (int tt = 0; tt < 4; ++tt)
          acc[cc][tt] += w[cc * 3 + 0] * iv[tt] + w[cc * 3 + 1] * iv[tt + 1] + w[cc * 3 + 2] * iv[tt + 2];
    }
    __syncthreads();
  }

#pragma unroll
  for (int cc = 0; cc < 4; ++cc) {
    int co = coBase + ty * 4 + cc;
    float bi = Bs[co];
    float sf = 0.f, df = 0.f;
    if (act == ACT_SIGMAP) {
      // geomspace(20, 11025, 128) oscillator bands
      double lg = log(551.25);                       // 11025/20
      double stop  = 20.0 * exp(lg * (double)co / 127.0);
      double start = (co == 0) ? 0.0 : 20.0 * exp(lg * (double)(co - 1) / 127.0);
      sf = (float)start;
      df = (float)(stop - start);
    }
    float4 v;
    float* vp = &v.x;
#pragma unroll
    for (int tt = 0; tt < 4; ++tt) {
      float z = acc[cc][tt] + bi;
      if (act == ACT_LRELU)       z = lrelu(z);
      else if (act == ACT_SIGMAP) z = sf + df / (1.f + expf(-z));
      else                        z = z * z;
      vp[tt] = z;
    }
    *reinterpret_cast<float4*>(&out[(size_t)(b * Cout + co) * 64 + tx * 4]) = v;
  }
}

// -------------------------------------------------------------------------
// Noise-path conv: nearest-x2 upsample + k=7 pad=3 conv, folded into a
// 4-tap conv on the UN-repeated input with parity-combined weights.
//   even out t=2s: taps m=s-2..s+1, weights {w0, w1+w2, w3+w4, w5+w6}
//   odd  out t=2s+1: taps m=s-1..s+2, weights {w0+w1, w2+w3, w4+w5, w6}
// Block: 128 thr = 16 co-quads (ty) x 8 s-quads (tx); tile = 64 co x 32 s.
// Weight LDS strided at 36 words per 4-co group: lane (ty) banks 4*ty -> all
// 32 banks covered per ds_read_b128, conflict-free (was 4-way at stride 32).
// -------------------------------------------------------------------------
__global__ void __launch_bounds__(128) conv_noise(
    const float* __restrict__ in, const float* __restrict__ W,
    const float* __restrict__ Bs, float* __restrict__ out,
    int Cin, int Tin)
{
  const int co0 = blockIdx.x * 64;
  const int s0  = blockIdx.y * 32;
  const int b   = blockIdx.z;
  const int tid = threadIdx.x;
  const int tx  = tid & 7;    // s quad (8 x 4 = 32 s)
  const int ty  = tid >> 3;   // co quad (16 x 4 = 64 co)

  __shared__ __align__(16) float inS[8][40];    // [ci][u], m = s0-2+u, u in [0,36)
  __shared__ __align__(16) float wS[8][576];    // [ci][(col>>2)*36 + (col&3)*8 + q]

  float accE[4][4] = {};
  float accO[4][4] = {};

  for (int ci0 = 0; ci0 < Cin; ci0 += 8) {
    for (int e = tid; e < 8 * 36; e += 128) {
      int ci = e / 36, u = e - ci * 36;
      int m = s0 - 2 + u;
      float v = 0.f;
      if (m >= 0 && m < Tin) v = in[(size_t)(b * Cin + ci0 + ci) * Tin + m];
      inS[ci][u] = v;
    }
    for (int e = tid; e < 8 * 64; e += 128) {
      int ci = e & 7, col = e >> 3;
      const float* wp = W + ((size_t)(co0 + col) * Cin + (ci0 + ci)) * 7;
      float w0 = wp[0], w1 = wp[1], w2 = wp[2], w3 = wp[3], w4 = wp[4], w5 = wp[5], w6 = wp[6];
      float4 ve = {w0,      w1 + w2, w3 + w4, w5 + w6};
      float4 vo = {w0 + w1, w2 + w3, w4 + w5, w6};
      float* d = &wS[ci][(col >> 2) * 36 + (col & 3) * 8];
      reinterpret_cast<float4*>(d)[0] = ve;
      reinterpret_cast<float4*>(d)[1] = vo;
    }
    __syncthreads();
#pragma unroll
    for (int ci = 0; ci < 8; ++ci) {
      const float4* ip = reinterpret_cast<const float4*>(&inS[ci][tx * 4]);
      float4 A0 = ip[0], A1 = ip[1];
      float iv[8] = {A0.x, A0.y, A0.z, A0.w, A1.x, A1.y, A1.z, A1.w};
      const float4* wrow = reinterpret_cast<const float4*>(&wS[ci][ty * 36]);
#pragma unroll
      for (int cc = 0; cc < 4; ++cc) {
        float4 we = wrow[cc * 2], wo = wrow[cc * 2 + 1];
#pragma unroll
        for (int ss = 0; ss < 4; ++ss) {
          accE[cc][ss] += we.x * iv[ss] + we.y * iv[ss + 1] + we.z * iv[ss + 2] + we.w * iv[ss + 3];
          accO[cc][ss] += wo.x * iv[ss + 1] + wo.y * iv[ss + 2] + wo.z * iv[ss + 3] + wo.w * iv[ss + 4];
        }
      }
    }
    __syncthreads();
  }

  const int T2 = Tin * 2;
#pragma unroll
  for (int cc = 0; cc < 4; ++cc) {
    int co = co0 + ty * 4 + cc;
    float bi = Bs[co];
    float4 v0, v1;
    v0.x = lrelu(accE[cc][0] + bi); v0.y = lrelu(accO[cc][0] + bi);
    v0.z = lrelu(accE[cc][1] + bi); v0.w = lrelu(accO[cc][1] + bi);
    v1.x = lrelu(accE[cc][2] + bi); v1.y = lrelu(accO[cc][2] + bi);
    v1.z = lrelu(accE[cc][3] + bi); v1.w = lrelu(accO[cc][3] + bi);
    float* op = out + (size_t)(b * 512 + co) * T2 + 2 * (s0 + tx * 4);
    reinterpret_cast<float4*>(op)[0] = v0;
    reinterpret_cast<float4*>(op)[1] = v1;
  }
}

// -------------------------------------------------------------------------
// Final noise conv: 512 -> 17 channels, k=3 pad=1, T=1024, output squared.
// -------------------------------------------------------------------------
__global__ void __launch_bounds__(256) conv_nl(
    const float* __restrict__ in, const float* __restrict__ W,
    const float* __restrict__ Bs, float* __restrict__ out)
{
  const int t0  = blockIdx.x * 64;
  const int b   = blockIdx.y;
  const int tid = threadIdx.x;
  const int tx  = tid & 15;
  const int cog = tid >> 4;

  __shared__ __align__(16) float inS[64][68];
  __shared__ float wS[64][52];

  float acc0[4] = {}, acc1[4] = {};
  const bool has2 = (cog == 0);

  for (int ci0 = 0; ci0 < 512; ci0 += 64) {
    for (int e = tid; e < 64 * 66; e += 256) {
      int ci = e / 66, u = e - ci * 66;
      int tin = t0 - 1 + u;
      float v = 0.f;
      if (tin >= 0 && tin < 1024) v = in[(size_t)(b * 512 + ci0 + ci) * 1024 + tin];
      inS[ci][u] = v;
    }
    for (int e = tid; e < 64 * 17; e += 256) {
      int col = e / 64, ci = e & 63;
      const float* wp = W + ((size_t)col * 512 + (ci0 + ci)) * 3;
      wS[ci][col * 3 + 0] = wp[0];
      wS[ci][col * 3 + 1] = wp[1];
      wS[ci][col * 3 + 2] = wp[2];
    }
    __syncthreads();
    for (int ci = 0; ci < 64; ++ci) {
      const float4* ip = reinterpret_cast<const float4*>(&inS[ci][tx * 4]);
      float4 i03 = ip[0];
      float2 i45 = *reinterpret_cast<const float2*>(&inS[ci][tx * 4 + 4]);
      float iv[6] = {i03.x, i03.y, i03.z, i03.w, i45.x, i45.y};
      float wA0 = wS[ci][cog * 3], wA1 = wS[ci][cog * 3 + 1], wA2 = wS[ci][cog * 3 + 2];
#pragma unroll
      for (int tt = 0; tt < 4; ++tt)
        acc0[tt] += wA0 * iv[tt] + wA1 * iv[tt + 1] + wA2 * iv[tt + 2];
      if (has2) {
        float wB0 = wS[ci][48], wB1 = wS[ci][49], wB2 = wS[ci][50];
#pragma unroll
        for (int tt = 0; tt < 4; ++tt)
          acc1[tt] += wB0 * iv[tt] + wB1 * iv[tt + 1] + wB2 * iv[tt + 2];
      }
    }
    __syncthreads();
  }

  {
    float bi = Bs[cog];
#pragma unroll
    for (int tt = 0; tt < 4; ++tt) {
      float z = acc0[tt] + bi;
      out[(size_t)(b * 17 + cog) * 1024 + t0 + tx * 4 + tt] = z * z;
    }
    if (has2) {
      float bi2 = Bs[16];
#pragma unroll
      for (int tt = 0; tt < 4; ++tt) {
        float z = acc1[tt] + bi2;
        out[(size_t)(b * 17 + 16) * 1024 + t0 + tx * 4 + tt] = z * z;
      }
    }
  }
}

// -------------------------------------------------------------------------
// Noise bank: per 32-sample frame, 17-bin real DFT * mags, inverse, store.
// -------------------------------------------------------------------------
__global__ void __launch_bounds__(256) noise_filter(
    const float* __restrict__ noise, const float* __restrict__ mags,
    float* __restrict__ filt)
{
  __shared__ float ct[32], st[32];
  int tid = threadIdx.x;
  if (tid < 32) {
    double a = (double)tid * (3.14159265358979323846 / 16.0);
    ct[tid] = (float)cos(a);
    st[tid] = (float)sin(a);
  }
  __syncthreads();

  int fidx = blockIdx.x * 256 + tid;
  int b = fidx >> 10, i = fidx & 1023;

  float xv[32];
#pragma unroll
  for (int n = 0; n < 32; ++n) {
    int idx = i * 16 + n;
    xv[n] = (idx < 16384) ? noise[(size_t)b * 16384 + idx] : 0.f;  // zero pad tail
  }

  float Yr[17], Yi[17];
#pragma unroll
  for (int k = 0; k <= 16; ++k) {
    float xr = 0.f, xi = 0.f;
    int kk = 0;
#pragma unroll
    for (int n = 0; n < 32; ++n) {
      xr += xv[n] * ct[kk];
      xi -= xv[n] * st[kk];
      kk = (kk + k) & 31;
    }
    float m = mags[((size_t)b * 17 + k) * 1024 + i];
    Yr[k] = xr * m;
    Yi[k] = xi * m;
  }

  float* fo = filt + ((size_t)b * 1024 + i) * 32;
#pragma unroll
  for (int n = 0; n < 32; ++n) {
    float v = Yr[0] + ((n & 1) ? -Yr[16] : Yr[16]);
    int kk = n;
#pragma unroll
    for (int k = 1; k <= 15; ++k) {
      v += 2.f * (Yr[k] * ct[kk] - Yi[k] * st[kk]);
      kk = (kk + n) & 31;
    }
    fo[n] = v * (1.f / 32.f);
  }
}

// -------------------------------------------------------------------------
// Oscillator bank. A 64-sample output chunk spans only 0.25 input index of
// the x256 linear upsample, so each (osc, chunk) needs just 3 endpoint
// values of f and a. Phase: f64 per-chunk bases (osc_phase) + f32 Kahan
// in-chunk accumulation, all in revolutions.
// -------------------------------------------------------------------------
static __device__ __forceinline__ int clamp64(int i) { return i < 0 ? 0 : (i > 63 ? 63 : i); }

// Pass 1: per (b,osc) row: per-64-chunk sums of f/sr, exclusive f64 scan.
__global__ void __launch_bounds__(256) osc_phase(
    const float* __restrict__ fsm, double* __restrict__ phaseBase)
{
  const int o = blockIdx.x, b = blockIdx.y;
  const float* frow = fsm + (size_t)(b * 128 + o) * 64;
  const int c = threadIdx.x;   // chunk

  const float ic0 = ((float)(c * 64) - 127.5f) * (1.0f / 256.0f);
  const int ilo = (int)floorf(ic0);
  float f0 = frow[clamp64(ilo)], f1 = frow[clamp64(ilo + 1)], f2 = frow[clamp64(ilo + 2)];

  double local = 0.0;
#pragma unroll 8
  for (int j = 0; j < 64; ++j) {
    float ic = ic0 + (float)j * (1.0f / 256.0f);
    float fl = floorf(ic);
    float w  = ic - fl;
    bool hi = ((int)fl) > ilo;
    float fa = hi ? f1 : f0;
    float fb = hi ? f2 : f1;
    float f = fa * (1.f - w) + fb * w;
    f = fminf(fmaxf(f, 20.f), 11025.f);
    local += (double)f;
  }
  local *= (1.0 / 22050.0);   // revolutions

  __shared__ double ps[256];
  ps[c] = local;
  __syncthreads();
  for (int off = 1; off < 256; off <<= 1) {
    double v = (c >= off) ? ps[c - off] : 0.0;
    __syncthreads();
    ps[c] += v;
    __syncthreads();
  }
  phaseBase[(size_t)(b * 128 + o) * 256 + c] = ps[c] - local;  // exclusive
}

// Pass 2: per (b, chunk): replay phase, sum sin*amp over 128 osc, add OLA
// noise, write output.
__global__ void __launch_bounds__(128) osc_sum(
    const float* __restrict__ fsm, const float* __restrict__ lsm,
    const double* __restrict__ phaseBase, const float* __restrict__ filt,
    float* __restrict__ out)
{
  const int c = blockIdx.x, b = blockIdx.y;
  const int tid = threadIdx.x;
  __shared__ float contrib[128][65];
  __shared__ float part[2][64];
  const int o = tid;
  const float* frow = fsm + (size_t)(b * 128 + o) * 64;
  const float* arow = lsm + (size_t)(b * 128 + o) * 64;

  double pb = phaseBase[(size_t)(b * 128 + o) * 256 + c];  // revolutions
  float fb0 = (float)(pb - floor(pb));

  const float ic0 = ((float)(c * 64) - 127.5f) * (1.0f / 256.0f);
  const int ilo = (int)floorf(ic0);
  float f0 = frow[clamp64(ilo)], f1 = frow[clamp64(ilo + 1)], f2 = frow[clamp64(ilo + 2)];
  float a0 = arow[clamp64(ilo)], a1 = arow[clamp64(ilo + 1)], a2 = arow[clamp64(ilo + 2)];

  float rel = 0.f, comp = 0.f;
#pragma unroll 8
  for (int j = 0; j < 64; ++j) {
    float ic = ic0 + (float)j * (1.0f / 256.0f);
    float fl = floorf(ic);
    float w  = ic - fl;
    bool hi = ((int)fl) > ilo;
    float fa = hi ? f1 : f0;
    float fb = hi ? f2 : f1;
    float f = fa * (1.f - w) + fb * w;
    f = fminf(fmaxf(f, 20.f), 11025.f);
    // Kahan-accumulate f/sr (revolutions)
    float y = f * (1.0f / 22050.0f) - comp;
    float t = rel + y;
    comp = (t - rel) - y;
    rel = t;
    float tot = fb0 + rel;
    float frac = tot - floorf(tot);
    float s = sinpif(2.f * frac);
    float aa = hi ? a1 : a0;
    float ab = hi ? a2 : a1;
    float am = aa * (1.f - w) + ab * w;
    contrib[o][j] = s * am;
  }
  __syncthreads();
  int half = tid >> 6, tl = tid & 63;
  float sum = 0.f;
  for (int oo = 0; oo < 64; ++oo) sum += contrib[half * 64 + oo][tl];
  part[half][tl] = sum;
  __syncthreads();
  if (tid < 64) {
    int t = c * 64 + tid;
    float v = part[0][tid] + part[1][tid];
    int i0 = t >> 4, r = t & 15;
    v += filt[((size_t)(b << 10) + i0) * 32 + r];
    if (i0 > 0) v += filt[((size_t)(b << 10) + i0 - 1) * 32 + 16 + r];
    out[(size_t)b * 16384 + t] = v;
  }
}

// -------------------------------------------------------------------------
extern "C" void kernel_launch(void* const* d_in, const int* in_sizes, int n_in,
                              void* d_out, int out_size, void* d_ws, size_t ws_size,
                              hipStream_t stream)
{
  (void)in_sizes; (void)n_in; (void)out_size; (void)ws_size;

  const float* x     = (const float*)d_in[0];
  const float* noise = (const float*)d_in[1];
  const float* mw0 = (const float*)d_in[2];  const float* mb0 = (const float*)d_in[3];
  const float* mw1 = (const float*)d_in[4];  const float* mb1 = (const float*)d_in[5];
  const float* mw2 = (const float*)d_in[6];  const float* mb2 = (const float*)d_in[7];
  const float* mw3 = (const float*)d_in[8];  const float* mb3 = (const float*)d_in[9];
  const float* fw  = (const float*)d_in[10]; const float* fb  = (const float*)d_in[11];
  const float* gw0 = (const float*)d_in[12]; const float* gb0 = (const float*)d_in[13];
  const float* gw1 = (const float*)d_in[14]; const float* gb1 = (const float*)d_in[15];
  const float* gw2 = (const float*)d_in[16]; const float* gb2 = (const float*)d_in[17];
  const float* gw3 = (const float*)d_in[18]; const float* gb3 = (const float*)d_in[19];
  const float* lw  = (const float*)d_in[20]; const float* lb  = (const float*)d_in[21];
  const float* nw0 = (const float*)d_in[22]; const float* nb0 = (const float*)d_in[23];
  const float* nw1 = (const float*)d_in[24]; const float* nb1 = (const float*)d_in[25];
  const float* nw2 = (const float*)d_in[26]; const float* nb2 = (const float*)d_in[27];
  const float* nw3 = (const float*)d_in[28]; const float* nb3 = (const float*)d_in[29];
  const float* nlw = (const float*)d_in[30]; const float* nlb = (const float*)d_in[31];

  float* ws = (float*)d_ws;
  // workspace layout (floats)
  float*  nbufA = ws;                       // noise l1/l3 out; also aliases hm/hg
  float*  nbufB = ws + 4194304;
  float*  fsm   = ws + 12582912;            // [16][128][64]
  float*  lsm   = ws + 12713984;
  float*  nl    = ws + 12845056;            // [16][17][1024]
  float*  filt  = ws + 13123584;            // [16][1024][32]
  double* phaseBase = (double*)(ws + 13647872);  // [16][128][256] doubles
  float* hm0 = nbufA;
  float* hm1 = nbufA + 524288;
  float* hg0 = nbufA + 1048576;
  float* hg1 = nbufA + 1572864;

  float* out = (float*)d_out;

  // frequency (m) + loudness (g) paths, fused
  conv_small<<<dim3(8, 16, 2), 256, 0, stream>>>(x, x, mw0, mb0, gw0, gb0, hm0, hg0, 128, 512, ACT_LRELU, ACT_LRELU);
  conv_small<<<dim3(8, 16, 2), 256, 0, stream>>>(hm0, hg0, mw1, mb1, gw1, gb1, hm1, hg1, 512, 512, ACT_LRELU, ACT_LRELU);
  conv_small<<<dim3(8, 16, 2), 256, 0, stream>>>(hm1, hg1, mw2, mb2, gw2, gb2, hm0, hg0, 512, 512, ACT_LRELU, ACT_LRELU);
  conv_small<<<dim3(8, 16, 2), 256, 0, stream>>>(hm0, hg0, mw3, mb3, gw3, gb3, hm1, hg1, 512, 512, ACT_LRELU, ACT_LRELU);
  conv_small<<<dim3(2, 16, 2), 256, 0, stream>>>(hm1, hg1, fw, fb, lw, lb, fsm, lsm, 512, 128, ACT_SIGMAP, ACT_SQUARE);

  // noise-envelope path (repeat-x2 folded into parity weights)
  conv_noise<<<dim3(8,  2, 16), 128, 0, stream>>>(x,     nw0, nb0, nbufA, 128, 64);
  conv_noise<<<dim3(8,  4, 16), 128, 0, stream>>>(nbufA, nw1, nb1, nbufB, 512, 128);
  conv_noise<<<dim3(8,  8, 16), 128, 0, stream>>>(nbufB, nw2, nb2, nbufA, 512, 256);
  conv_noise<<<dim3(8, 16, 16), 128, 0, stream>>>(nbufA, nw3, nb3, nbufB, 512, 512);
  conv_nl<<<dim3(16, 16), 256, 0, stream>>>(nbufB, nlw, nlb, nl);

  // filtered noise frames
  noise_filter<<<dim3(64), 256, 0, stream>>>(noise, nl, filt);

  // oscillator bank + final sum (includes overlap-add of noise frames)
  osc_phase<<<dim3(128, 16), 256, 0, stream>>>(fsm, phaseBase);
  osc_sum<<<dim3(256, 16), 128, 0, stream>>>(fsm, lsm, phaseBase, filt, out);
}

// Round 3
// 1304.597 us; speedup vs baseline: 2.6223x; 2.6223x over previous
//
#include <hip/hip_runtime.h>
#include <math.h>

#define ACT_LRELU  0
#define ACT_SIGMAP 1
#define ACT_SQUARE 2

typedef __attribute__((ext_vector_type(8))) short v8s;
typedef __attribute__((ext_vector_type(4))) short v4s;
typedef __attribute__((ext_vector_type(4))) float f32x4;

static __device__ __forceinline__ float lrelu(float x) { return x >= 0.f ? x : 0.2f * x; }

// round-to-nearest-even fp32 -> bf16 (bit pattern)
static __device__ __forceinline__ short bf16rne(float x) {
  unsigned u = __float_as_uint(x);
  unsigned r = (u + 0x7FFFu + ((u >> 16) & 1u)) >> 16;
  return (short)r;
}
static __device__ __forceinline__ float bf16tof(short h) {
  return __uint_as_float(((unsigned)(unsigned short)h) << 16);
}

// -------------------------------------------------------------------------
// Small conv: k=3, pad=1, T=64. Two independent paths fused via blockIdx.z.
// -------------------------------------------------------------------------
__global__ void __launch_bounds__(256) conv_small(
    const float* __restrict__ inm, const float* __restrict__ ing,
    const float* __restrict__ Wm, const float* __restrict__ Bm,
    const float* __restrict__ Wg, const float* __restrict__ Bg,
    float* __restrict__ outm, float* __restrict__ outg,
    int Cin, int Cout, int actm, int actg)
{
  const int p = blockIdx.z;
  const float* in = p ? ing : inm;
  const float* W  = p ? Wg  : Wm;
  const float* Bs = p ? Bg  : Bm;
  float* out      = p ? outg : outm;
  const int act   = p ? actg : actm;

  const int coBase = blockIdx.x * 64;
  const int b   = blockIdx.y;
  const int tid = threadIdx.x;
  const int tx  = tid & 15;   // t quad
  const int ty  = tid >> 4;   // co quad

  __shared__ __align__(16) float inS[64][68];
  __shared__ __align__(16) float wS[64][192];

  float acc[4][4] = {};

  for (int ci0 = 0; ci0 < Cin; ci0 += 64) {
    for (int e = tid; e < 64 * 66; e += 256) {
      int ci = e / 66, u = e - ci * 66;
      int tin = u - 1;
      float v = 0.f;
      if (tin >= 0 && tin < 64) v = in[(size_t)(b * Cin + ci0 + ci) * 64 + tin];
      inS[ci][u] = v;
    }
    for (int e = tid; e < 64 * 64; e += 256) {
      int col = e >> 6, ci = e & 63;
      const float* wp = W + ((size_t)(coBase + col) * Cin + (ci0 + ci)) * 3;
      wS[ci][col * 3 + 0] = wp[0];
      wS[ci][col * 3 + 1] = wp[1];
      wS[ci][col * 3 + 2] = wp[2];
    }
    __syncthreads();
    for (int ci = 0; ci < 64; ++ci) {
      const float4* ip = reinterpret_cast<const float4*>(&inS[ci][tx * 4]);
      float4 i03 = ip[0];
      float2 i45 = *reinterpret_cast<const float2*>(&inS[ci][tx * 4 + 4]);
      float iv[6] = {i03.x, i03.y, i03.z, i03.w, i45.x, i45.y};
      const float4* wp4 = reinterpret_cast<const float4*>(&wS[ci][ty * 12]);
      float4 wa = wp4[0], wb = wp4[1], wc = wp4[2];
      float w[12] = {wa.x, wa.y, wa.z, wa.w, wb.x, wb.y, wb.z, wb.w, wc.x, wc.y, wc.z, wc.w};
#pragma unroll
      for (int cc = 0; cc < 4; ++cc)
#pragma unroll
        for (int tt = 0; tt < 4; ++tt)
          acc[cc][tt] += w[cc * 3 + 0] * iv[tt] + w[cc * 3 + 1] * iv[tt + 1] + w[cc * 3 + 2] * iv[tt + 2];
    }
    __syncthreads();
  }

#pragma unroll
  for (int cc = 0; cc < 4; ++cc) {
    int co = coBase + ty * 4 + cc;
    float bi = Bs[co];
    float sf = 0.f, df = 0.f;
    if (act == ACT_SIGMAP) {
      double lg = log(551.25);
      double stop  = 20.0 * exp(lg * (double)co / 127.0);
      double start = (co == 0) ? 0.0 : 20.0 * exp(lg * (double)(co - 1) / 127.0);
      sf = (float)start;
      df = (float)(stop - start);
    }
    float4 v;
    float* vp = &v.x;
#pragma unroll
    for (int tt = 0; tt < 4; ++tt) {
      float z = acc[cc][tt] + bi;
      if (act == ACT_LRELU)       z = lrelu(z);
      else if (act == ACT_SIGMAP) z = sf + df / (1.f + expf(-z));
      else                        z = z * z;
      vp[tt] = z;
    }
    *reinterpret_cast<float4*>(&out[(size_t)(b * Cout + co) * 64 + tx * 4]) = v;
  }
}

// -------------------------------------------------------------------------
// Weight prep for noise conv: fold k=7 + nearest-x2 into 4-tap parity
// weights, split each into bf16 hi/lo.
// Panel layout: Ag[((par*2+plane)*512 + co)*K + ci*4 + q], K = Cin*4.
// -------------------------------------------------------------------------
__global__ void __launch_bounds__(256) fold_weights(
    const float* __restrict__ W, short* __restrict__ Ag, int Cin)
{
  int idx = blockIdx.x * 256 + threadIdx.x;   // co*Cin + ci
  if (idx >= 512 * Cin) return;
  int co = idx / Cin, ci = idx - co * Cin;
  const float* wp = W + (size_t)idx * 7;
  float w0 = wp[0], w1 = wp[1], w2 = wp[2], w3 = wp[3], w4 = wp[4], w5 = wp[5], w6 = wp[6];
  float fold[2][4] = {{w0, w1 + w2, w3 + w4, w5 + w6},
                      {w0 + w1, w2 + w3, w4 + w5, w6}};
  const int K = Cin * 4;
#pragma unroll
  for (int par = 0; par < 2; ++par) {
    v4s hi, lo;
#pragma unroll
    for (int q = 0; q < 4; ++q) {
      float v = fold[par][q];
      short h = bf16rne(v);
      hi[q] = h;
      lo[q] = bf16rne(v - bf16tof(h));
    }
    *reinterpret_cast<v4s*>(&Ag[((size_t)((par * 2 + 0) * 512 + co)) * K + ci * 4]) = hi;
    *reinterpret_cast<v4s*>(&Ag[((size_t)((par * 2 + 1) * 512 + co)) * K + ci * 4]) = lo;
  }
}

// -------------------------------------------------------------------------
// Noise conv as split-bf16 MFMA GEMM.
//   M = 512 co (per parity), K = Cin*4 (ci x 4 folded taps), N = s within b.
//   C[co][s] -> out[b][co][2*s+par], lrelu(.+bias).
// Tiles: BM=128, BN=128, BK=32. 256 thr = 4 waves (2x2), wave tile 64x64.
// Split: x = hi + lo (bf16 each); acc += Ah*Bh + Ah*Bl + Al*Bh.
// LDS rows padded to 40 bf16 (80B) -> b128 ops at the 8-cycle BW floor.
// Grid: 1-D, nwg = 8 * ntpb * B, XCD-grouped so the 8 (m-tile,par) blocks
// sharing one B-slice land on one XCD (d&7 = XCD id on MI355X).
// -------------------------------------------------------------------------
__global__ void __launch_bounds__(256) conv_noise_mfma(
    const float* __restrict__ in, const short* __restrict__ Ag,
    const float* __restrict__ Bs, float* __restrict__ out,
    int Cin, int Sout, int Q, int ntpb)
{
  const int K = Cin * 4;
  const int Sin = Sout;

  // XCD-grouped decode
  int d = blockIdx.x;
  int idx = (d & 7) * Q + (d >> 3);
  int m8  = idx & 7;           // par*4 + m-tile
  int par = m8 >> 2;
  int co0 = (m8 & 3) * 128;
  int rest = idx >> 3;
  int nt = rest % ntpb;
  int b  = rest / ntpb;
  int s0 = nt * 128;
  int s_off = par ? -1 : -2;

  const int tid = threadIdx.x;
  const int w   = tid >> 6;
  const int wm  = w & 1, wn = w >> 1;
  const int l   = tid & 63;
  const int row = l & 15, kg = l >> 4;

  __shared__ __align__(16) short Alds[2][128 * 40];
  __shared__ __align__(16) short Blds[2][128 * 40];

  f32x4 acc[4][4] = {};

  for (int k0 = 0; k0 < K; k0 += 32) {
    // ---- stage A (pre-split panel, 2 planes x 128co x 32k) ----
#pragma unroll
    for (int p = 0; p < 2; ++p)
#pragma unroll
      for (int c = 0; c < 2; ++c) {
        int e = c * 256 + tid;
        int co_l = e >> 2, kq = e & 3;
        const v8s* gp = reinterpret_cast<const v8s*>(
            &Ag[((size_t)((par * 2 + p) * 512 + co0 + co_l)) * K + k0 + kq * 8]);
        *reinterpret_cast<v8s*>(&Alds[p][co_l * 40 + kq * 8]) = *gp;
      }
    // ---- stage B from fp32 activations (fused im2col + hi/lo split) ----
    {
      const int ci_base = k0 >> 2;
#pragma unroll
      for (int it = 0; it < 4; ++it) {
        int p = it * 256 + tid;
        int n = p & 127;
        int ci_l = p >> 7;                  // 0..7
        const float* src = in + ((size_t)(b * Cin) + ci_base + ci_l) * Sin;
        int sb = s0 + n + s_off;
        v4s hi, lo;
#pragma unroll
        for (int q = 0; q < 4; ++q) {
          int sg = sb + q;
          float v = (sg >= 0 && sg < Sin) ? src[sg] : 0.f;
          short h = bf16rne(v);
          hi[q] = h;
          lo[q] = bf16rne(v - bf16tof(h));
        }
        *reinterpret_cast<v4s*>(&Blds[0][n * 40 + ci_l * 4]) = hi;
        *reinterpret_cast<v4s*>(&Blds[1][n * 40 + ci_l * 4]) = lo;
      }
    }
    __syncthreads();

    // ---- fragments + MFMA ----
    const int ab = (wm * 64 + row) * 40 + kg * 8;
    const int bb = (wn * 64 + row) * 40 + kg * 8;
    v8s ah[4], al[4], bh[4], bl[4];
#pragma unroll
    for (int f = 0; f < 4; ++f) {
      ah[f] = *reinterpret_cast<const v8s*>(&Alds[0][ab + f * 640]);
      al[f] = *reinterpret_cast<const v8s*>(&Alds[1][ab + f * 640]);
      bh[f] = *reinterpret_cast<const v8s*>(&Blds[0][bb + f * 640]);
      bl[f] = *reinterpret_cast<const v8s*>(&Blds[1][bb + f * 640]);
    }
#pragma unroll
    for (int fm = 0; fm < 4; ++fm)
#pragma unroll
      for (int fn = 0; fn < 4; ++fn) {
        acc[fm][fn] = __builtin_amdgcn_mfma_f32_16x16x32_bf16(ah[fm], bh[fn], acc[fm][fn], 0, 0, 0);
        acc[fm][fn] = __builtin_amdgcn_mfma_f32_16x16x32_bf16(ah[fm], bl[fn], acc[fm][fn], 0, 0, 0);
        acc[fm][fn] = __builtin_amdgcn_mfma_f32_16x16x32_bf16(al[fm], bh[fn], acc[fm][fn], 0, 0, 0);
      }
    __syncthreads();
  }

  // ---- epilogue: bias + lrelu, write out[b][co][2*s+par] ----
  const int r4 = (l >> 4) * 4, cl = l & 15;
  const int T2 = 2 * Sout;
#pragma unroll
  for (int fm = 0; fm < 4; ++fm) {
    int co = co0 + wm * 64 + fm * 16 + r4;
    float4 bia = *reinterpret_cast<const float4*>(&Bs[co]);
    const float* bp = &bia.x;
#pragma unroll
    for (int fn = 0; fn < 4; ++fn) {
      int s = s0 + wn * 64 + fn * 16 + cl;
      if (s < Sout) {
#pragma unroll
        for (int r = 0; r < 4; ++r) {
          float z = lrelu(acc[fm][fn][r] + bp[r]);
          out[((size_t)(b * 512) + co + r) * T2 + 2 * s + par] = z;
        }
      }
    }
  }
}

// -------------------------------------------------------------------------
// Final noise conv: 512 -> 17 channels, k=3 pad=1, T=1024, output squared.
// -------------------------------------------------------------------------
__global__ void __launch_bounds__(256) conv_nl(
    const float* __restrict__ in, const float* __restrict__ W,
    const float* __restrict__ Bs, float* __restrict__ out)
{
  const int t0  = blockIdx.x * 64;
  const int b   = blockIdx.y;
  const int tid = threadIdx.x;
  const int tx  = tid & 15;
  const int cog = tid >> 4;

  __shared__ __align__(16) float inS[64][68];
  __shared__ float wS[64][52];

  float acc0[4] = {}, acc1[4] = {};
  const bool has2 = (cog == 0);

  for (int ci0 = 0; ci0 < 512; ci0 += 64) {
    for (int e = tid; e < 64 * 66; e += 256) {
      int ci = e / 66, u = e - ci * 66;
      int tin = t0 - 1 + u;
      float v = 0.f;
      if (tin >= 0 && tin < 1024) v = in[(size_t)(b * 512 + ci0 + ci) * 1024 + tin];
      inS[ci][u] = v;
    }
    for (int e = tid; e < 64 * 17; e += 256) {
      int col = e / 64, ci = e & 63;
      const float* wp = W + ((size_t)col * 512 + (ci0 + ci)) * 3;
      wS[ci][col * 3 + 0] = wp[0];
      wS[ci][col * 3 + 1] = wp[1];
      wS[ci][col * 3 + 2] = wp[2];
    }
    __syncthreads();
    for (int ci = 0; ci < 64; ++ci) {
      const float4* ip = reinterpret_cast<const float4*>(&inS[ci][tx * 4]);
      float4 i03 = ip[0];
      float2 i45 = *reinterpret_cast<const float2*>(&inS[ci][tx * 4 + 4]);
      float iv[6] = {i03.x, i03.y, i03.z, i03.w, i45.x, i45.y};
      float wA0 = wS[ci][cog * 3], wA1 = wS[ci][cog * 3 + 1], wA2 = wS[ci][cog * 3 + 2];
#pragma unroll
      for (int tt = 0; tt < 4; ++tt)
        acc0[tt] += wA0 * iv[tt] + wA1 * iv[tt + 1] + wA2 * iv[tt + 2];
      if (has2) {
        float wB0 = wS[ci][48], wB1 = wS[ci][49], wB2 = wS[ci][50];
#pragma unroll
        for (int tt = 0; tt < 4; ++tt)
          acc1[tt] += wB0 * iv[tt] + wB1 * iv[tt + 1] + wB2 * iv[tt + 2];
      }
    }
    __syncthreads();
  }

  {
    float bi = Bs[cog];
#pragma unroll
    for (int tt = 0; tt < 4; ++tt) {
      float z = acc0[tt] + bi;
      out[(size_t)(b * 17 + cog) * 1024 + t0 + tx * 4 + tt] = z * z;
    }
    if (has2) {
      float bi2 = Bs[16];
#pragma unroll
      for (int tt = 0; tt < 4; ++tt) {
        float z = acc1[tt] + bi2;
        out[(size_t)(b * 17 + 16) * 1024 + t0 + tx * 4 + tt] = z * z;
      }
    }
  }
}

// -------------------------------------------------------------------------
// Noise bank: per 32-sample frame, 17-bin real DFT * mags, inverse, store.
// -------------------------------------------------------------------------
__global__ void __launch_bounds__(256) noise_filter(
    const float* __restrict__ noise, const float* __restrict__ mags,
    float* __restrict__ filt)
{
  __shared__ float ct[32], st[32];
  int tid = threadIdx.x;
  if (tid < 32) {
    double a = (double)tid * (3.14159265358979323846 / 16.0);
    ct[tid] = (float)cos(a);
    st[tid] = (float)sin(a);
  }
  __syncthreads();

  int fidx = blockIdx.x * 256 + tid;
  int b = fidx >> 10, i = fidx & 1023;

  float xv[32];
#pragma unroll
  for (int n = 0; n < 32; ++n) {
    int idx = i * 16 + n;
    xv[n] = (idx < 16384) ? noise[(size_t)b * 16384 + idx] : 0.f;
  }

  float Yr[17], Yi[17];
#pragma unroll
  for (int k = 0; k <= 16; ++k) {
    float xr = 0.f, xi = 0.f;
    int kk = 0;
#pragma unroll
    for (int n = 0; n < 32; ++n) {
      xr += xv[n] * ct[kk];
      xi -= xv[n] * st[kk];
      kk = (kk + k) & 31;
    }
    float m = mags[((size_t)b * 17 + k) * 1024 + i];
    Yr[k] = xr * m;
    Yi[k] = xi * m;
  }

  float* fo = filt + ((size_t)b * 1024 + i) * 32;
#pragma unroll
  for (int n = 0; n < 32; ++n) {
    float v = Yr[0] + ((n & 1) ? -Yr[16] : Yr[16]);
    int kk = n;
#pragma unroll
    for (int k = 1; k <= 15; ++k) {
      v += 2.f * (Yr[k] * ct[kk] - Yi[k] * st[kk]);
      kk = (kk + n) & 31;
    }
    fo[n] = v * (1.f / 32.f);
  }
}

// -------------------------------------------------------------------------
// Oscillator bank (3-point lerp endpoints + f64 chunk base + f32 Kahan).
// -------------------------------------------------------------------------
static __device__ __forceinline__ int clamp64(int i) { return i < 0 ? 0 : (i > 63 ? 63 : i); }

__global__ void __launch_bounds__(256) osc_phase(
    const float* __restrict__ fsm, double* __restrict__ phaseBase)
{
  const int o = blockIdx.x, b = blockIdx.y;
  const float* frow = fsm + (size_t)(b * 128 + o) * 64;
  const int c = threadIdx.x;

  const float ic0 = ((float)(c * 64) - 127.5f) * (1.0f / 256.0f);
  const int ilo = (int)floorf(ic0);
  float f0 = frow[clamp64(ilo)], f1 = frow[clamp64(ilo + 1)], f2 = frow[clamp64(ilo + 2)];

  double local = 0.0;
#pragma unroll 8
  for (int j = 0; j < 64; ++j) {
    float ic = ic0 + (float)j * (1.0f / 256.0f);
    float fl = floorf(ic);
    float w  = ic - fl;
    bool hi = ((int)fl) > ilo;
    float fa = hi ? f1 : f0;
    float fb = hi ? f2 : f1;
    float f = fa * (1.f - w) + fb * w;
    f = fminf(fmaxf(f, 20.f), 11025.f);
    local += (double)f;
  }
  local *= (1.0 / 22050.0);

  __shared__ double ps[256];
  ps[c] = local;
  __syncthreads();
  for (int off = 1; off < 256; off <<= 1) {
    double v = (c >= off) ? ps[c - off] : 0.0;
    __syncthreads();
    ps[c] += v;
    __syncthreads();
  }
  phaseBase[(size_t)(b * 128 + o) * 256 + c] = ps[c] - local;
}

__global__ void __launch_bounds__(128) osc_sum(
    const float* __restrict__ fsm, const float* __restrict__ lsm,
    const double* __restrict__ phaseBase, const float* __restrict__ filt,
    float* __restrict__ out)
{
  const int c = blockIdx.x, b = blockIdx.y;
  const int tid = threadIdx.x;
  __shared__ float contrib[128][65];
  __shared__ float part[2][64];
  const int o = tid;
  const float* frow = fsm + (size_t)(b * 128 + o) * 64;
  const float* arow = lsm + (size_t)(b * 128 + o) * 64;

  double pb = phaseBase[(size_t)(b * 128 + o) * 256 + c];
  float fb0 = (float)(pb - floor(pb));

  const float ic0 = ((float)(c * 64) - 127.5f) * (1.0f / 256.0f);
  const int ilo = (int)floorf(ic0);
  float f0 = frow[clamp64(ilo)], f1 = frow[clamp64(ilo + 1)], f2 = frow[clamp64(ilo + 2)];
  float a0 = arow[clamp64(ilo)], a1 = arow[clamp64(ilo + 1)], a2 = arow[clamp64(ilo + 2)];

  float rel = 0.f, comp = 0.f;
#pragma unroll 8
  for (int j = 0; j < 64; ++j) {
    float ic = ic0 + (float)j * (1.0f / 256.0f);
    float fl = floorf(ic);
    float w  = ic - fl;
    bool hi = ((int)fl) > ilo;
    float fa = hi ? f1 : f0;
    float fb = hi ? f2 : f1;
    float f = fa * (1.f - w) + fb * w;
    f = fminf(fmaxf(f, 20.f), 11025.f);
    float y = f * (1.0f / 22050.0f) - comp;
    float t = rel + y;
    comp = (t - rel) - y;
    rel = t;
    float tot = fb0 + rel;
    float frac = tot - floorf(tot);
    float s = sinpif(2.f * frac);
    float aa = hi ? a1 : a0;
    float ab = hi ? a2 : a1;
    float am = aa * (1.f - w) + ab * w;
    contrib[o][j] = s * am;
  }
  __syncthreads();
  int half = tid >> 6, tl = tid & 63;
  float sum = 0.f;
  for (int oo = 0; oo < 64; ++oo) sum += contrib[half * 64 + oo][tl];
  part[half][tl] = sum;
  __syncthreads();
  if (tid < 64) {
    int t = c * 64 + tid;
    float v = part[0][tid] + part[1][tid];
    int i0 = t >> 4, r = t & 15;
    v += filt[((size_t)(b << 10) + i0) * 32 + r];
    if (i0 > 0) v += filt[((size_t)(b << 10) + i0 - 1) * 32 + 16 + r];
    out[(size_t)b * 16384 + t] = v;
  }
}

// -------------------------------------------------------------------------
extern "C" void kernel_launch(void* const* d_in, const int* in_sizes, int n_in,
                              void* d_out, int out_size, void* d_ws, size_t ws_size,
                              hipStream_t stream)
{
  (void)in_sizes; (void)n_in; (void)out_size; (void)ws_size;

  const float* x     = (const float*)d_in[0];
  const float* noise = (const float*)d_in[1];
  const float* mw0 = (const float*)d_in[2];  const float* mb0 = (const float*)d_in[3];
  const float* mw1 = (const float*)d_in[4];  const float* mb1 = (const float*)d_in[5];
  const float* mw2 = (const float*)d_in[6];  const float* mb2 = (const float*)d_in[7];
  const float* mw3 = (const float*)d_in[8];  const float* mb3 = (const float*)d_in[9];
  const float* fw  = (const float*)d_in[10]; const float* fb  = (const float*)d_in[11];
  const float* gw0 = (const float*)d_in[12]; const float* gb0 = (const float*)d_in[13];
  const float* gw1 = (const float*)d_in[14]; const float* gb1 = (const float*)d_in[15];
  const float* gw2 = (const float*)d_in[16]; const float* gb2 = (const float*)d_in[17];
  const float* gw3 = (const float*)d_in[18]; const float* gb3 = (const float*)d_in[19];
  const float* lw  = (const float*)d_in[20]; const float* lb  = (const float*)d_in[21];
  const float* nw0 = (const float*)d_in[22]; const float* nb0 = (const float*)d_in[23];
  const float* nw1 = (const float*)d_in[24]; const float* nb1 = (const float*)d_in[25];
  const float* nw2 = (const float*)d_in[26]; const float* nb2 = (const float*)d_in[27];
  const float* nw3 = (const float*)d_in[28]; const float* nb3 = (const float*)d_in[29];
  const float* nlw = (const float*)d_in[30]; const float* nlb = (const float*)d_in[31];

  float* ws = (float*)d_ws;
  // workspace layout (float slots):
  float*  nbufA = ws;                            // activations ping
  float*  nbufB = ws + 4194304;                  // activations pong
  float*  fsm   = ws + 12582912;                 // [16][128][64]
  float*  lsm   = ws + 12713984;
  float*  nl    = ws + 12845056;                 // [16][17][1024]
  float*  filt  = ws + 13123584;                 // [16][1024][32]
  double* phaseBase = (double*)(ws + 13647872);  // [16][128][256] doubles
  // bf16 A-panel (8.4 MB, reused per layer). Aliases phaseBase region:
  // panel is only live during the noise convs, phaseBase only afterwards.
  short*  panel = (short*)(ws + 13647872);       // high-water: 15,745,024 floats (63 MB)
  float* hm0 = nbufA;
  float* hm1 = nbufA + 524288;
  float* hg0 = nbufA + 1048576;
  float* hg1 = nbufA + 1572864;

  float* out = (float*)d_out;

  // frequency (m) + loudness (g) paths, fused
  conv_small<<<dim3(8, 16, 2), 256, 0, stream>>>(x, x, mw0, mb0, gw0, gb0, hm0, hg0, 128, 512, ACT_LRELU, ACT_LRELU);
  conv_small<<<dim3(8, 16, 2), 256, 0, stream>>>(hm0, hg0, mw1, mb1, gw1, gb1, hm1, hg1, 512, 512, ACT_LRELU, ACT_LRELU);
  conv_small<<<dim3(8, 16, 2), 256, 0, stream>>>(hm1, hg1, mw2, mb2, gw2, gb2, hm0, hg0, 512, 512, ACT_LRELU, ACT_LRELU);
  conv_small<<<dim3(8, 16, 2), 256, 0, stream>>>(hm0, hg0, mw3, mb3, gw3, gb3, hm1, hg1, 512, 512, ACT_LRELU, ACT_LRELU);
  conv_small<<<dim3(2, 16, 2), 256, 0, stream>>>(hm1, hg1, fw, fb, lw, lb, fsm, lsm, 512, 128, ACT_SIGMAP, ACT_SQUARE);

  // noise-envelope path: fold weights -> split-bf16 MFMA GEMM per layer
  fold_weights<<<(512 * 128 + 255) / 256, 256, 0, stream>>>(nw0, panel, 128);
  conv_noise_mfma<<<128, 256, 0, stream>>>(x,     panel, nb0, nbufA, 128, 64,  16, 1);
  fold_weights<<<(512 * 512 + 255) / 256, 256, 0, stream>>>(nw1, panel, 512);
  conv_noise_mfma<<<128, 256, 0, stream>>>(nbufA, panel, nb1, nbufB, 512, 128, 16, 1);
  fold_weights<<<(512 * 512 + 255) / 256, 256, 0, stream>>>(nw2, panel, 512);
  conv_noise_mfma<<<256, 256, 0, stream>>>(nbufB, panel, nb2, nbufA, 512, 256, 32, 2);
  fold_weights<<<(512 * 512 + 255) / 256, 256, 0, stream>>>(nw3, panel, 512);
  conv_noise_mfma<<<512, 256, 0, stream>>>(nbufA, panel, nb3, nbufB, 512, 512, 64, 4);

  conv_nl<<<dim3(16, 16), 256, 0, stream>>>(nbufB, nlw, nlb, nl);

  // filtered noise frames
  noise_filter<<<dim3(64), 256, 0, stream>>>(noise, nl, filt);

  // oscillator bank + final sum (includes overlap-add of noise frames)
  osc_phase<<<dim3(128, 16), 256, 0, stream>>>(fsm, phaseBase);
  osc_sum<<<dim3(256, 16), 128, 0, stream>>>(fsm, lsm, phaseBase, filt, out);
}

// Round 4
// 1268.158 us; speedup vs baseline: 2.6976x; 1.0287x over previous
//
#include <hip/hip_runtime.h>
#include <math.h>

#define ACT_LRELU  0
#define ACT_SIGMAP 1
#define ACT_SQUARE 2

typedef __attribute__((ext_vector_type(8))) short v8s;
typedef __attribute__((ext_vector_type(4))) short v4s;
typedef __attribute__((ext_vector_type(4))) float f32x4;

static __device__ __forceinline__ float lrelu(float x) { return x >= 0.f ? x : 0.2f * x; }

// round-to-nearest-even fp32 -> bf16 (bit pattern)
static __device__ __forceinline__ short bf16rne(float x) {
  unsigned u = __float_as_uint(x);
  unsigned r = (u + 0x7FFFu + ((u >> 16) & 1u)) >> 16;
  return (short)r;
}
static __device__ __forceinline__ float bf16tof(short h) {
  return __uint_as_float(((unsigned)(unsigned short)h) << 16);
}

// -------------------------------------------------------------------------
// x[b][ci][t] -> xT[b][t][ci]   (16 x 128 x 64, tiny)
// -------------------------------------------------------------------------
__global__ void __launch_bounds__(256) xpose_x(
    const float* __restrict__ x, float* __restrict__ xT)
{
  const int b = blockIdx.x;
  for (int e = threadIdx.x; e < 128 * 64; e += 256) {
    int ci = e >> 6, t = e & 63;
    xT[((size_t)(b * 64) + t) * 128 + ci] = x[((size_t)(b * 128) + ci) * 64 + t];
  }
}

// -------------------------------------------------------------------------
// Panel prep for path convs: W[Cout][Cin][3] -> Ag[plane][co][tap*Cin+ci],
// 3 bf16 planes (hi, lo, lo2) ~= fp32 precision. Dual (m,g) via blockIdx.y.
// -------------------------------------------------------------------------
__global__ void __launch_bounds__(256) prep_panel3_dual(
    const float* __restrict__ Wm, const float* __restrict__ Wg,
    short* __restrict__ AgM, short* __restrict__ AgG, int Cin, int Cout)
{
  int idx = blockIdx.x * 256 + threadIdx.x;
  if (idx >= Cout * Cin) return;
  const float* W = blockIdx.y ? Wg : Wm;
  short* Ag      = blockIdx.y ? AgG : AgM;
  int co = idx / Cin, ci = idx - co * Cin;
  const int K3 = 3 * Cin;
  const float* wp = W + (size_t)idx * 3;
#pragma unroll
  for (int tap = 0; tap < 3; ++tap) {
    float v = wp[tap];
    short h = bf16rne(v);  float r1 = v - bf16tof(h);
    short s1 = bf16rne(r1); float r2 = r1 - bf16tof(s1);
    short s2 = bf16rne(r2);
    size_t base = (size_t)tap * Cin + ci;
    Ag[(size_t)(0 * Cout + co) * K3 + base] = h;
    Ag[(size_t)(1 * Cout + co) * K3 + base] = s1;
    Ag[(size_t)(2 * Cout + co) * K3 + base] = s2;
  }
}

// -------------------------------------------------------------------------
// m/g path conv as 3-plane split-bf16 MFMA GEMM (~fp32 precision).
//   M = Cout, K = 3*Cin (tap-major), N = B*64 (b,t).
//   in:  [b][t][ci] fp32.   out (LRELU): [b][t][co] fp32.
//   out (SIGMAP): fsm[b][co][t]; out (SQUARE): lsm[b][co][t].
// Tiles BM=BN=128, BK=32; 256 thr = 4 waves (2x2), wave tile 64x64.
// Products kept (>= 2^-24): hh, hl, lh, ll, hq, qh  -> 6 MFMA / frag pair.
// Grid: (8 n-tiles, Cout/128, 2 paths).
// -------------------------------------------------------------------------
__global__ void __launch_bounds__(256) conv_path_mfma(
    const float* __restrict__ inM, const float* __restrict__ inG,
    const short* __restrict__ AgM, const short* __restrict__ AgG,
    const float* __restrict__ BsM, const float* __restrict__ BsG,
    float* __restrict__ outM, float* __restrict__ outG,
    int Cin, int Cout, int actM, int actG)
{
  const int nt = blockIdx.x;
  const int mt = blockIdx.y;
  const int path = blockIdx.z;
  const float* in = path ? inG : inM;
  const short* Ag = path ? AgG : AgM;
  const float* Bs = path ? BsG : BsM;
  float* out      = path ? outG : outM;
  const int act   = path ? actG : actM;

  const int K3 = 3 * Cin;
  const int co0 = mt * 128;
  const int n0  = nt * 128;

  const int tid = threadIdx.x;
  const int w = tid >> 6, wm = w & 1, wn = w >> 1;
  const int l = tid & 63;
  const int row = l & 15, kg = l >> 4;

  __shared__ __align__(16) short Al[3][128 * 40];
  __shared__ __align__(16) short Bl[3][128 * 40];
  __shared__ float bandS[2][128];

  if (act == ACT_SIGMAP && tid < 128) {
    double lg = log(551.25);
    double stop  = 20.0 * exp(lg * (double)tid / 127.0);
    double start = (tid == 0) ? 0.0 : 20.0 * exp(lg * (double)(tid - 1) / 127.0);
    bandS[0][tid] = (float)start;
    bandS[1][tid] = (float)(stop - start);
  }

  f32x4 acc[4][4] = {};

  for (int tap = 0; tap < 3; ++tap) {
    for (int ci0 = 0; ci0 < Cin; ci0 += 32) {
      const int k0 = tap * Cin + ci0;
      // ---- stage A: 3 planes x 128 co x 32 k ----
#pragma unroll
      for (int p = 0; p < 3; ++p)
#pragma unroll
        for (int c = 0; c < 2; ++c) {
          int e = c * 256 + tid;
          int co_l = e >> 2, kq = e & 3;
          v8s vv = *reinterpret_cast<const v8s*>(
              &Ag[(size_t)(p * Cout + co0 + co_l) * K3 + k0 + kq * 8]);
          *reinterpret_cast<v8s*>(&Al[p][co_l * 40 + kq * 8]) = vv;
        }
      // ---- stage B: 128 n x 32 k, fused 3-way split ----
#pragma unroll
      for (int it = 0; it < 4; ++it) {
        int e = it * 256 + tid;
        int n = e & 127, cig = e >> 7;       // cig 0..7
        int gn = n0 + n;
        int bb = gn >> 6, t = gn & 63;
        int trow = t + tap - 1;
        float4 v = {0.f, 0.f, 0.f, 0.f};
        if (trow >= 0 && trow < 64)
          v = *reinterpret_cast<const float4*>(
              &in[(size_t)(bb * 64 + trow) * Cin + ci0 + cig * 4]);
        const float* vp = &v.x;
        v4s hi, lo, qo;
#pragma unroll
        for (int q = 0; q < 4; ++q) {
          float x0 = vp[q];
          short h  = bf16rne(x0); float r1 = x0 - bf16tof(h);
          short s1 = bf16rne(r1); float r2 = r1 - bf16tof(s1);
          short s2 = bf16rne(r2);
          hi[q] = h; lo[q] = s1; qo[q] = s2;
        }
        *reinterpret_cast<v4s*>(&Bl[0][n * 40 + cig * 4]) = hi;
        *reinterpret_cast<v4s*>(&Bl[1][n * 40 + cig * 4]) = lo;
        *reinterpret_cast<v4s*>(&Bl[2][n * 40 + cig * 4]) = qo;
      }
      __syncthreads();

      const int ab = (wm * 64 + row) * 40 + kg * 8;
      const int bb2 = (wn * 64 + row) * 40 + kg * 8;
      v8s ah[4], bh[4];
#pragma unroll
      for (int f = 0; f < 4; ++f) {
        ah[f] = *reinterpret_cast<const v8s*>(&Al[0][ab + f * 640]);
        bh[f] = *reinterpret_cast<const v8s*>(&Bl[0][bb2 + f * 640]);
      }
#pragma unroll
      for (int fm = 0; fm < 4; ++fm)
#pragma unroll
        for (int fn = 0; fn < 4; ++fn)
          acc[fm][fn] = __builtin_amdgcn_mfma_f32_16x16x32_bf16(ah[fm], bh[fn], acc[fm][fn], 0, 0, 0);
      {
        v8s al[4], bl[4];
#pragma unroll
        for (int f = 0; f < 4; ++f) {
          al[f] = *reinterpret_cast<const v8s*>(&Al[1][ab + f * 640]);
          bl[f] = *reinterpret_cast<const v8s*>(&Bl[1][bb2 + f * 640]);
        }
#pragma unroll
        for (int fm = 0; fm < 4; ++fm)
#pragma unroll
          for (int fn = 0; fn < 4; ++fn) {
            acc[fm][fn] = __builtin_amdgcn_mfma_f32_16x16x32_bf16(ah[fm], bl[fn], acc[fm][fn], 0, 0, 0);
            acc[fm][fn] = __builtin_amdgcn_mfma_f32_16x16x32_bf16(al[fm], bh[fn], acc[fm][fn], 0, 0, 0);
            acc[fm][fn] = __builtin_amdgcn_mfma_f32_16x16x32_bf16(al[fm], bl[fn], acc[fm][fn], 0, 0, 0);
          }
      }
      {
        v8s aq[4], bq[4];
#pragma unroll
        for (int f = 0; f < 4; ++f) {
          aq[f] = *reinterpret_cast<const v8s*>(&Al[2][ab + f * 640]);
          bq[f] = *reinterpret_cast<const v8s*>(&Bl[2][bb2 + f * 640]);
        }
#pragma unroll
        for (int fm = 0; fm < 4; ++fm)
#pragma unroll
          for (int fn = 0; fn < 4; ++fn) {
            acc[fm][fn] = __builtin_amdgcn_mfma_f32_16x16x32_bf16(ah[fm], bq[fn], acc[fm][fn], 0, 0, 0);
            acc[fm][fn] = __builtin_amdgcn_mfma_f32_16x16x32_bf16(aq[fm], bh[fn], acc[fm][fn], 0, 0, 0);
          }
      }
      __syncthreads();
    }
  }

  // ---- epilogue ----
  const int colL = l & 15, rowB = (l >> 4) * 4;
#pragma unroll
  for (int fm = 0; fm < 4; ++fm) {
    int co = co0 + wm * 64 + fm * 16 + rowB;
    float4 bia = *reinterpret_cast<const float4*>(&Bs[co]);
    const float* bp = &bia.x;
#pragma unroll
    for (int fn = 0; fn < 4; ++fn) {
      int gn = n0 + wn * 64 + fn * 16 + colL;
      int bb = gn >> 6, t = gn & 63;
      if (act == ACT_LRELU) {
        float4 vo;
        float* vp = &vo.x;
#pragma unroll
        for (int r = 0; r < 4; ++r) vp[r] = lrelu(acc[fm][fn][r] + bp[r]);
        *reinterpret_cast<float4*>(&out[(size_t)(bb * 64 + t) * Cout + co]) = vo;
      } else if (act == ACT_SIGMAP) {
#pragma unroll
        for (int r = 0; r < 4; ++r) {
          float z = acc[fm][fn][r] + bp[r];
          float f = bandS[0][co + r] + bandS[1][co + r] / (1.f + expf(-z));
          out[(size_t)(bb * 128 + co + r) * 64 + t] = f;
        }
      } else {  // ACT_SQUARE
#pragma unroll
        for (int r = 0; r < 4; ++r) {
          float z = acc[fm][fn][r] + bp[r];
          out[(size_t)(bb * 128 + co + r) * 64 + t] = z * z;
        }
      }
    }
  }
}

// -------------------------------------------------------------------------
// Weight prep for noise conv: fold k=7 + nearest-x2 into 4-tap parity
// weights, split each into bf16 hi/lo.
// -------------------------------------------------------------------------
__global__ void __launch_bounds__(256) fold_weights(
    const float* __restrict__ W, short* __restrict__ Ag, int Cin)
{
  int idx = blockIdx.x * 256 + threadIdx.x;   // co*Cin + ci
  if (idx >= 512 * Cin) return;
  int co = idx / Cin, ci = idx - co * Cin;
  const float* wp = W + (size_t)idx * 7;
  float w0 = wp[0], w1 = wp[1], w2 = wp[2], w3 = wp[3], w4 = wp[4], w5 = wp[5], w6 = wp[6];
  float fold[2][4] = {{w0, w1 + w2, w3 + w4, w5 + w6},
                      {w0 + w1, w2 + w3, w4 + w5, w6}};
  const int K = Cin * 4;
#pragma unroll
  for (int par = 0; par < 2; ++par) {
    v4s hi, lo;
#pragma unroll
    for (int q = 0; q < 4; ++q) {
      float v = fold[par][q];
      short h = bf16rne(v);
      hi[q] = h;
      lo[q] = bf16rne(v - bf16tof(h));
    }
    *reinterpret_cast<v4s*>(&Ag[((size_t)((par * 2 + 0) * 512 + co)) * K + ci * 4]) = hi;
    *reinterpret_cast<v4s*>(&Ag[((size_t)((par * 2 + 1) * 512 + co)) * K + ci * 4]) = lo;
  }
}

// -------------------------------------------------------------------------
// Noise conv as split-bf16 MFMA GEMM (hi/lo, 3 products — amplitude path).
// -------------------------------------------------------------------------
__global__ void __launch_bounds__(256) conv_noise_mfma(
    const float* __restrict__ in, const short* __restrict__ Ag,
    const float* __restrict__ Bs, float* __restrict__ out,
    int Cin, int Sout, int Q, int ntpb)
{
  const int K = Cin * 4;
  const int Sin = Sout;

  int d = blockIdx.x;
  int idx = (d & 7) * Q + (d >> 3);
  int m8  = idx & 7;
  int par = m8 >> 2;
  int co0 = (m8 & 3) * 128;
  int rest = idx >> 3;
  int nt = rest % ntpb;
  int b  = rest / ntpb;
  int s0 = nt * 128;
  int s_off = par ? -1 : -2;

  const int tid = threadIdx.x;
  const int w   = tid >> 6;
  const int wm  = w & 1, wn = w >> 1;
  const int l   = tid & 63;
  const int row = l & 15, kg = l >> 4;

  __shared__ __align__(16) short Alds[2][128 * 40];
  __shared__ __align__(16) short Blds[2][128 * 40];

  f32x4 acc[4][4] = {};

  for (int k0 = 0; k0 < K; k0 += 32) {
#pragma unroll
    for (int p = 0; p < 2; ++p)
#pragma unroll
      for (int c = 0; c < 2; ++c) {
        int e = c * 256 + tid;
        int co_l = e >> 2, kq = e & 3;
        const v8s* gp = reinterpret_cast<const v8s*>(
            &Ag[((size_t)((par * 2 + p) * 512 + co0 + co_l)) * K + k0 + kq * 8]);
        *reinterpret_cast<v8s*>(&Alds[p][co_l * 40 + kq * 8]) = *gp;
      }
    {
      const int ci_base = k0 >> 2;
#pragma unroll
      for (int it = 0; it < 4; ++it) {
        int p = it * 256 + tid;
        int n = p & 127;
        int ci_l = p >> 7;
        const float* src = in + ((size_t)(b * Cin) + ci_base + ci_l) * Sin;
        int sb = s0 + n + s_off;
        v4s hi, lo;
#pragma unroll
        for (int q = 0; q < 4; ++q) {
          int sg = sb + q;
          float v = (sg >= 0 && sg < Sin) ? src[sg] : 0.f;
          short h = bf16rne(v);
          hi[q] = h;
          lo[q] = bf16rne(v - bf16tof(h));
        }
        *reinterpret_cast<v4s*>(&Blds[0][n * 40 + ci_l * 4]) = hi;
        *reinterpret_cast<v4s*>(&Blds[1][n * 40 + ci_l * 4]) = lo;
      }
    }
    __syncthreads();

    const int ab = (wm * 64 + row) * 40 + kg * 8;
    const int bb = (wn * 64 + row) * 40 + kg * 8;
    v8s ah[4], al[4], bh[4], bl[4];
#pragma unroll
    for (int f = 0; f < 4; ++f) {
      ah[f] = *reinterpret_cast<const v8s*>(&Alds[0][ab + f * 640]);
      al[f] = *reinterpret_cast<const v8s*>(&Alds[1][ab + f * 640]);
      bh[f] = *reinterpret_cast<const v8s*>(&Blds[0][bb + f * 640]);
      bl[f] = *reinterpret_cast<const v8s*>(&Blds[1][bb + f * 640]);
    }
#pragma unroll
    for (int fm = 0; fm < 4; ++fm)
#pragma unroll
      for (int fn = 0; fn < 4; ++fn) {
        acc[fm][fn] = __builtin_amdgcn_mfma_f32_16x16x32_bf16(ah[fm], bh[fn], acc[fm][fn], 0, 0, 0);
        acc[fm][fn] = __builtin_amdgcn_mfma_f32_16x16x32_bf16(ah[fm], bl[fn], acc[fm][fn], 0, 0, 0);
        acc[fm][fn] = __builtin_amdgcn_mfma_f32_16x16x32_bf16(al[fm], bh[fn], acc[fm][fn], 0, 0, 0);
      }
    __syncthreads();
  }

  const int r4 = (l >> 4) * 4, cl = l & 15;
  const int T2 = 2 * Sout;
#pragma unroll
  for (int fm = 0; fm < 4; ++fm) {
    int co = co0 + wm * 64 + fm * 16 + r4;
    float4 bia = *reinterpret_cast<const float4*>(&Bs[co]);
    const float* bp = &bia.x;
#pragma unroll
    for (int fn = 0; fn < 4; ++fn) {
      int s = s0 + wn * 64 + fn * 16 + cl;
      if (s < Sout) {
#pragma unroll
        for (int r = 0; r < 4; ++r) {
          float z = lrelu(acc[fm][fn][r] + bp[r]);
          out[((size_t)(b * 512) + co + r) * T2 + 2 * s + par] = z;
        }
      }
    }
  }
}

// -------------------------------------------------------------------------
// Final noise conv: 512 -> 17 channels, k=3 pad=1, T=1024, output squared.
// -------------------------------------------------------------------------
__global__ void __launch_bounds__(256) conv_nl(
    const float* __restrict__ in, const float* __restrict__ W,
    const float* __restrict__ Bs, float* __restrict__ out)
{
  const int t0  = blockIdx.x * 64;
  const int b   = blockIdx.y;
  const int tid = threadIdx.x;
  const int tx  = tid & 15;
  const int cog = tid >> 4;

  __shared__ __align__(16) float inS[64][68];
  __shared__ float wS[64][52];

  float acc0[4] = {}, acc1[4] = {};
  const bool has2 = (cog == 0);

  for (int ci0 = 0; ci0 < 512; ci0 += 64) {
    for (int e = tid; e < 64 * 66; e += 256) {
      int ci = e / 66, u = e - ci * 66;
      int tin = t0 - 1 + u;
      float v = 0.f;
      if (tin >= 0 && tin < 1024) v = in[(size_t)(b * 512 + ci0 + ci) * 1024 + tin];
      inS[ci][u] = v;
    }
    for (int e = tid; e < 64 * 17; e += 256) {
      int col = e / 64, ci = e & 63;
      const float* wp = W + ((size_t)col * 512 + (ci0 + ci)) * 3;
      wS[ci][col * 3 + 0] = wp[0];
      wS[ci][col * 3 + 1] = wp[1];
      wS[ci][col * 3 + 2] = wp[2];
    }
    __syncthreads();
    for (int ci = 0; ci < 64; ++ci) {
      const float4* ip = reinterpret_cast<const float4*>(&inS[ci][tx * 4]);
      float4 i03 = ip[0];
      float2 i45 = *reinterpret_cast<const float2*>(&inS[ci][tx * 4 + 4]);
      float iv[6] = {i03.x, i03.y, i03.z, i03.w, i45.x, i45.y};
      float wA0 = wS[ci][cog * 3], wA1 = wS[ci][cog * 3 + 1], wA2 = wS[ci][cog * 3 + 2];
#pragma unroll
      for (int tt = 0; tt < 4; ++tt)
        acc0[tt] += wA0 * iv[tt] + wA1 * iv[tt + 1] + wA2 * iv[tt + 2];
      if (has2) {
        float wB0 = wS[ci][48], wB1 = wS[ci][49], wB2 = wS[ci][50];
#pragma unroll
        for (int tt = 0; tt < 4; ++tt)
          acc1[tt] += wB0 * iv[tt] + wB1 * iv[tt + 1] + wB2 * iv[tt + 2];
      }
    }
    __syncthreads();
  }

  {
    float bi = Bs[cog];
#pragma unroll
    for (int tt = 0; tt < 4; ++tt) {
      float z = acc0[tt] + bi;
      out[(size_t)(b * 17 + cog) * 1024 + t0 + tx * 4 + tt] = z * z;
    }
    if (has2) {
      float bi2 = Bs[16];
#pragma unroll
      for (int tt = 0; tt < 4; ++tt) {
        float z = acc1[tt] + bi2;
        out[(size_t)(b * 17 + 16) * 1024 + t0 + tx * 4 + tt] = z * z;
      }
    }
  }
}

// -------------------------------------------------------------------------
// Noise bank: per 32-sample frame, 17-bin real DFT * mags, inverse, store.
// -------------------------------------------------------------------------
__global__ void __launch_bounds__(256) noise_filter(
    const float* __restrict__ noise, const float* __restrict__ mags,
    float* __restrict__ filt)
{
  __shared__ float ct[32], st[32];
  int tid = threadIdx.x;
  if (tid < 32) {
    double a = (double)tid * (3.14159265358979323846 / 16.0);
    ct[tid] = (float)cos(a);
    st[tid] = (float)sin(a);
  }
  __syncthreads();

  int fidx = blockIdx.x * 256 + tid;
  int b = fidx >> 10, i = fidx & 1023;

  float xv[32];
#pragma unroll
  for (int n = 0; n < 32; ++n) {
    int idx = i * 16 + n;
    xv[n] = (idx < 16384) ? noise[(size_t)b * 16384 + idx] : 0.f;
  }

  float Yr[17], Yi[17];
#pragma unroll
  for (int k = 0; k <= 16; ++k) {
    float xr = 0.f, xi = 0.f;
    int kk = 0;
#pragma unroll
    for (int n = 0; n < 32; ++n) {
      xr += xv[n] * ct[kk];
      xi -= xv[n] * st[kk];
      kk = (kk + k) & 31;
    }
    float m = mags[((size_t)b * 17 + k) * 1024 + i];
    Yr[k] = xr * m;
    Yi[k] = xi * m;
  }

  float* fo = filt + ((size_t)b * 1024 + i) * 32;
#pragma unroll
  for (int n = 0; n < 32; ++n) {
    float v = Yr[0] + ((n & 1) ? -Yr[16] : Yr[16]);
    int kk = n;
#pragma unroll
    for (int k = 1; k <= 15; ++k) {
      v += 2.f * (Yr[k] * ct[kk] - Yi[k] * st[kk]);
      kk = (kk + n) & 31;
    }
    fo[n] = v * (1.f / 32.f);
  }
}

// -------------------------------------------------------------------------
// Oscillator bank (3-point lerp endpoints + f64 chunk base + f32 Kahan).
// -------------------------------------------------------------------------
static __device__ __forceinline__ int clamp64(int i) { return i < 0 ? 0 : (i > 63 ? 63 : i); }

__global__ void __launch_bounds__(256) osc_phase(
    const float* __restrict__ fsm, double* __restrict__ phaseBase)
{
  const int o = blockIdx.x, b = blockIdx.y;
  const float* frow = fsm + (size_t)(b * 128 + o) * 64;
  const int c = threadIdx.x;

  const float ic0 = ((float)(c * 64) - 127.5f) * (1.0f / 256.0f);
  const int ilo = (int)floorf(ic0);
  float f0 = frow[clamp64(ilo)], f1 = frow[clamp64(ilo + 1)], f2 = frow[clamp64(ilo + 2)];

  double local = 0.0;
#pragma unroll 8
  for (int j = 0; j < 64; ++j) {
    float ic = ic0 + (float)j * (1.0f / 256.0f);
    float fl = floorf(ic);
    float w  = ic - fl;
    bool hi = ((int)fl) > ilo;
    float fa = hi ? f1 : f0;
    float fb = hi ? f2 : f1;
    float f = fa * (1.f - w) + fb * w;
    f = fminf(fmaxf(f, 20.f), 11025.f);
    local += (double)f;
  }
  local *= (1.0 / 22050.0);

  __shared__ double ps[256];
  ps[c] = local;
  __syncthreads();
  for (int off = 1; off < 256; off <<= 1) {
    double v = (c >= off) ? ps[c - off] : 0.0;
    __syncthreads();
    ps[c] += v;
    __syncthreads();
  }
  phaseBase[(size_t)(b * 128 + o) * 256 + c] = ps[c] - local;
}

__global__ void __launch_bounds__(128) osc_sum(
    const float* __restrict__ fsm, const float* __restrict__ lsm,
    const double* __restrict__ phaseBase, const float* __restrict__ filt,
    float* __restrict__ out)
{
  const int c = blockIdx.x, b = blockIdx.y;
  const int tid = threadIdx.x;
  __shared__ float contrib[128][65];
  __shared__ float part[2][64];
  const int o = tid;
  const float* frow = fsm + (size_t)(b * 128 + o) * 64;
  const float* arow = lsm + (size_t)(b * 128 + o) * 64;

  double pb = phaseBase[(size_t)(b * 128 + o) * 256 + c];
  float fb0 = (float)(pb - floor(pb));

  const float ic0 = ((float)(c * 64) - 127.5f) * (1.0f / 256.0f);
  const int ilo = (int)floorf(ic0);
  float f0 = frow[clamp64(ilo)], f1 = frow[clamp64(ilo + 1)], f2 = frow[clamp64(ilo + 2)];
  float a0 = arow[clamp64(ilo)], a1 = arow[clamp64(ilo + 1)], a2 = arow[clamp64(ilo + 2)];

  float rel = 0.f, comp = 0.f;
#pragma unroll 8
  for (int j = 0; j < 64; ++j) {
    float ic = ic0 + (float)j * (1.0f / 256.0f);
    float fl = floorf(ic);
    float w  = ic - fl;
    bool hi = ((int)fl) > ilo;
    float fa = hi ? f1 : f0;
    float fb = hi ? f2 : f1;
    float f = fa * (1.f - w) + fb * w;
    f = fminf(fmaxf(f, 20.f), 11025.f);
    float y = f * (1.0f / 22050.0f) - comp;
    float t = rel + y;
    comp = (t - rel) - y;
    rel = t;
    float tot = fb0 + rel;
    float frac = tot - floorf(tot);
    float s = sinpif(2.f * frac);
    float aa = hi ? a1 : a0;
    float ab = hi ? a2 : a1;
    float am = aa * (1.f - w) + ab * w;
    contrib[o][j] = s * am;
  }
  __syncthreads();
  int half = tid >> 6, tl = tid & 63;
  float sum = 0.f;
  for (int oo = 0; oo < 64; ++oo) sum += contrib[half * 64 + oo][tl];
  part[half][tl] = sum;
  __syncthreads();
  if (tid < 64) {
    int t = c * 64 + tid;
    float v = part[0][tid] + part[1][tid];
    int i0 = t >> 4, r = t & 15;
    v += filt[((size_t)(b << 10) + i0) * 32 + r];
    if (i0 > 0) v += filt[((size_t)(b << 10) + i0 - 1) * 32 + 16 + r];
    out[(size_t)b * 16384 + t] = v;
  }
}

// -------------------------------------------------------------------------
extern "C" void kernel_launch(void* const* d_in, const int* in_sizes, int n_in,
                              void* d_out, int out_size, void* d_ws, size_t ws_size,
                              hipStream_t stream)
{
  (void)in_sizes; (void)n_in; (void)out_size; (void)ws_size;

  const float* x     = (const float*)d_in[0];
  const float* noise = (const float*)d_in[1];
  const float* mw0 = (const float*)d_in[2];  const float* mb0 = (const float*)d_in[3];
  const float* mw1 = (const float*)d_in[4];  const float* mb1 = (const float*)d_in[5];
  const float* mw2 = (const float*)d_in[6];  const float* mb2 = (const float*)d_in[7];
  const float* mw3 = (const float*)d_in[8];  const float* mb3 = (const float*)d_in[9];
  const float* fw  = (const float*)d_in[10]; const float* fb  = (const float*)d_in[11];
  const float* gw0 = (const float*)d_in[12]; const float* gb0 = (const float*)d_in[13];
  const float* gw1 = (const float*)d_in[14]; const float* gb1 = (const float*)d_in[15];
  const float* gw2 = (const float*)d_in[16]; const float* gb2 = (const float*)d_in[17];
  const float* gw3 = (const float*)d_in[18]; const float* gb3 = (const float*)d_in[19];
  const float* lw  = (const float*)d_in[20]; const float* lb  = (const float*)d_in[21];
  const float* nw0 = (const float*)d_in[22]; const float* nb0 = (const float*)d_in[23];
  const float* nw1 = (const float*)d_in[24]; const float* nb1 = (const float*)d_in[25];
  const float* nw2 = (const float*)d_in[26]; const float* nb2 = (const float*)d_in[27];
  const float* nw3 = (const float*)d_in[28]; const float* nb3 = (const float*)d_in[29];
  const float* nlw = (const float*)d_in[30]; const float* nlb = (const float*)d_in[31];

  float* ws = (float*)d_ws;
  // workspace layout (float slots):
  float*  nbufA = ws;                            // noise l1/l3 out (4,194,304)
  float*  nbufB = ws + 4194304;                  // noise l2/l4 out (8,388,608)
  float*  fsm   = ws + 12582912;                 // [16][128][64]
  float*  lsm   = ws + 12713984;
  float*  nl    = ws + 12845056;                 // [16][17][1024]
  float*  filt  = ws + 13123584;                 // [16][1024][32]
  double* phaseBase = (double*)(ws + 13647872);  // [16][128][256] doubles
  short*  npanel = (short*)(ws + 13647872);      // noise panel (aliases phaseBase; disjoint in time)
  // path-phase aliases (dead before noise path starts):
  float*  hm0 = nbufA;                 // [16][64][512] activations, [b][t][ci]
  float*  hm1 = nbufA + 524288;
  float*  hg0 = nbufA + 1048576;
  float*  hg1 = nbufA + 1572864;
  float*  xT  = nbufA + 2097152;       // [16][64][128]
  short*  panelM = (short*)(ws + 4194304);       // 3*512*1536 shorts
  short*  panelG = (short*)(ws + 5373952);

  float* out = (float*)d_out;

  // ---- m/g paths: 3-plane split-bf16 MFMA convs ----
  xpose_x<<<dim3(16), 256, 0, stream>>>(x, xT);
  prep_panel3_dual<<<dim3((512 * 128 + 255) / 256, 2), 256, 0, stream>>>(mw0, gw0, panelM, panelG, 128, 512);
  conv_path_mfma<<<dim3(8, 4, 2), 256, 0, stream>>>(xT, xT, panelM, panelG, mb0, gb0, hm0, hg0, 128, 512, ACT_LRELU, ACT_LRELU);
  prep_panel3_dual<<<dim3((512 * 512 + 255) / 256, 2), 256, 0, stream>>>(mw1, gw1, panelM, panelG, 512, 512);
  conv_path_mfma<<<dim3(8, 4, 2), 256, 0, stream>>>(hm0, hg0, panelM, panelG, mb1, gb1, hm1, hg1, 512, 512, ACT_LRELU, ACT_LRELU);
  prep_panel3_dual<<<dim3((512 * 512 + 255) / 256, 2), 256, 0, stream>>>(mw2, gw2, panelM, panelG, 512, 512);
  conv_path_mfma<<<dim3(8, 4, 2), 256, 0, stream>>>(hm1, hg1, panelM, panelG, mb2, gb2, hm0, hg0, 512, 512, ACT_LRELU, ACT_LRELU);
  prep_panel3_dual<<<dim3((512 * 512 + 255) / 256, 2), 256, 0, stream>>>(mw3, gw3, panelM, panelG, 512, 512);
  conv_path_mfma<<<dim3(8, 4, 2), 256, 0, stream>>>(hm0, hg0, panelM, panelG, mb3, gb3, hm1, hg1, 512, 512, ACT_LRELU, ACT_LRELU);
  prep_panel3_dual<<<dim3((128 * 512 + 255) / 256, 2), 256, 0, stream>>>(fw, lw, panelM, panelG, 512, 128);
  conv_path_mfma<<<dim3(8, 1, 2), 256, 0, stream>>>(hm1, hg1, panelM, panelG, fb, lb, fsm, lsm, 512, 128, ACT_SIGMAP, ACT_SQUARE);

  // ---- noise-envelope path: fold weights -> split-bf16 MFMA GEMM ----
  fold_weights<<<(512 * 128 + 255) / 256, 256, 0, stream>>>(nw0, npanel, 128);
  conv_noise_mfma<<<128, 256, 0, stream>>>(x,     npanel, nb0, nbufA, 128, 64,  16, 1);
  fold_weights<<<(512 * 512 + 255) / 256, 256, 0, stream>>>(nw1, npanel, 512);
  conv_noise_mfma<<<128, 256, 0, stream>>>(nbufA, npanel, nb1, nbufB, 512, 128, 16, 1);
  fold_weights<<<(512 * 512 + 255) / 256, 256, 0, stream>>>(nw2, npanel, 512);
  conv_noise_mfma<<<256, 256, 0, stream>>>(nbufB, npanel, nb2, nbufA, 512, 256, 32, 2);
  fold_weights<<<(512 * 512 + 255) / 256, 256, 0, stream>>>(nw3, npanel, 512);
  conv_noise_mfma<<<512, 256, 0, stream>>>(nbufA, npanel, nb3, nbufB, 512, 512, 64, 4);

  conv_nl<<<dim3(16, 16), 256, 0, stream>>>(nbufB, nlw, nlb, nl);

  // ---- filtered noise frames ----
  noise_filter<<<dim3(64), 256, 0, stream>>>(noise, nl, filt);

  // ---- oscillator bank + final sum ----
  osc_phase<<<dim3(128, 16), 256, 0, stream>>>(fsm, phaseBase);
  osc_sum<<<dim3(256, 16), 128, 0, stream>>>(fsm, lsm, phaseBase, filt, out);
}

// Round 5
// 839.498 us; speedup vs baseline: 4.0751x; 1.5106x over previous
//
#include <hip/hip_runtime.h>
#include <math.h>

#define ACT_LRELU  0
#define ACT_SIGMAP 1
#define ACT_SQUARE 2

typedef __attribute__((ext_vector_type(8))) short v8s;
typedef __attribute__((ext_vector_type(4))) short v4s;
typedef __attribute__((ext_vector_type(16))) float f32x16;

static __device__ __forceinline__ float lrelu(float x) { return x >= 0.f ? x : 0.2f * x; }

static __device__ __forceinline__ short bf16rne(float x) {
  unsigned u = __float_as_uint(x);
  unsigned r = (u + 0x7FFFu + ((u >> 16) & 1u)) >> 16;
  return (short)r;
}
static __device__ __forceinline__ float bf16tof(short h) {
  return __uint_as_float(((unsigned)(unsigned short)h) << 16);
}
static __device__ __forceinline__ void split3(float v, short& h, short& l, short& q) {
  h = bf16rne(v); float r1 = v - bf16tof(h);
  l = bf16rne(r1); float r2 = r1 - bf16tof(l);
  q = bf16rne(r2);
}

// -------------------------------------------------------------------------
// prep_acts: x[b][128][64] -> xm3[pl][b][t][ci], 3 bf16 planes (~exact fp32)
// -------------------------------------------------------------------------
__global__ void __launch_bounds__(256) prep_acts(
    const float* __restrict__ x, short* __restrict__ xm3)
{
  int e = blockIdx.x * 256 + threadIdx.x;
  if (e >= 131072) return;
  int b = e >> 13, rem = e & 8191, t = rem >> 7, ci = rem & 127;
  float v = x[((size_t)(b * 128) + ci) * 64 + t];
  short h, l, q; split3(v, h, l, q);
  size_t o = ((size_t)(b * 64) + t) * 128 + ci;
  xm3[0 * 131072 + o] = h;
  xm3[1 * 131072 + o] = l;
  xm3[2 * 131072 + o] = q;
}

// -------------------------------------------------------------------------
// prep_panels: all 5 m/g layers, both paths. W[Cout][Cin][3] ->
// P[pl][co][tap*Cin+ci] (3 bf16 planes, tap-major K).
// -------------------------------------------------------------------------
__global__ void __launch_bounds__(256) prep_panels(
    const float* mw0, const float* mw1, const float* mw2, const float* mw3, const float* fw,
    const float* gw0, const float* gw1, const float* gw2, const float* gw3, const float* lw,
    short* __restrict__ mP, short* __restrict__ gP)
{
  int i = blockIdx.x * 256 + threadIdx.x;
  const int PER_PATH = 917504;
  if (i >= 2 * PER_PATH) return;
  int path = i >= PER_PATH ? 1 : 0;
  int r = i - path * PER_PATH;
  int layer, Cin, Cout; size_t poff;
  if (r < 65536)       { layer = 0;               Cin = 128; Cout = 512; poff = 0; }
  else if (r < 327680) { layer = 1; r -= 65536;   Cin = 512; Cout = 512; poff = 589824; }
  else if (r < 589824) { layer = 2; r -= 327680;  Cin = 512; Cout = 512; poff = 2949120; }
  else if (r < 851968) { layer = 3; r -= 589824;  Cin = 512; Cout = 512; poff = 5308416; }
  else                 { layer = 4; r -= 851968;  Cin = 512; Cout = 128; poff = 7667712; }
  const float* Wm[5] = {mw0, mw1, mw2, mw3, fw};
  const float* Wg[5] = {gw0, gw1, gw2, gw3, lw};
  const float* W = path ? Wg[layer] : Wm[layer];
  short* P = (path ? gP : mP) + poff;
  int co = r / Cin, ci = r - co * Cin;
  const int K3 = 3 * Cin;
  const float* wp = W + (size_t)(co * Cin + ci) * 3;
#pragma unroll
  for (int tap = 0; tap < 3; ++tap) {
    short h, l, q; split3(wp[tap], h, l, q);
    size_t base = (size_t)co * K3 + tap * Cin + ci;
    P[(size_t)0 * Cout * K3 + base] = h;
    P[(size_t)1 * Cout * K3 + base] = l;
    P[(size_t)2 * Cout * K3 + base] = q;
  }
}

// -------------------------------------------------------------------------
// m/g path conv: 3-plane split-bf16 MFMA GEMM, 32x32x16, ~fp32 precision.
//   M = Cout, K = 3*Cin tap-major, N = 16b*64t.
// Tile 64x64, BK=64, 4 waves (2x2), wave tile 32x32 (1 frag).
// Products: hh, hl, lh, ll, hq, qh.
// Grid nblk = 2*(Cout/64)*16, XCD-grouped (blocks sharing B-slice -> 1 XCD).
// -------------------------------------------------------------------------
__global__ void __launch_bounds__(256) conv_path(
    const short* __restrict__ actM, const short* __restrict__ actG,
    const short* __restrict__ Pm, const short* __restrict__ Pg,
    const float* __restrict__ BsM, const float* __restrict__ BsG,
    float* __restrict__ foutM, float* __restrict__ foutG,
    short* __restrict__ soutM, short* __restrict__ soutG,
    int Cin, int Cout, int psIn, int psOut, int actMk, int actGk)
{
  const int mtiles = Cout >> 6;
  const int nblk = 2 * mtiles * 16;
  const int Q = nblk >> 3;
  int d = blockIdx.x;
  int idx = (d & 7) * Q + (d >> 3);
  int mt = idx % mtiles;
  int tmp = idx / mtiles;
  int nt = tmp & 15;
  int path = tmp >> 4;

  const short* act = path ? actG : actM;
  const short* P   = path ? Pg : Pm;
  const float* Bs  = path ? BsG : BsM;
  float* fout      = path ? foutG : foutM;
  short* sout      = path ? soutG : soutM;
  const int actk   = path ? actGk : actMk;

  const int K3 = 3 * Cin;
  const int co0 = mt * 64;
  const int n0  = nt * 64;

  const int tid = threadIdx.x;
  const int w = tid >> 6, wm = w & 1, wn = w >> 1;
  const int l = tid & 63;

  __shared__ __align__(16) short Al[3][64 * 72];
  __shared__ __align__(16) short Bl[3][64 * 72];
  __shared__ float bandS[2][128];

  if (actk == ACT_SIGMAP && tid < 128) {
    double lg = log(551.25);
    double stop  = 20.0 * exp(lg * (double)tid / 127.0);
    double start = (tid == 0) ? 0.0 : 20.0 * exp(lg * (double)(tid - 1) / 127.0);
    bandS[0][tid] = (float)start;
    bandS[1][tid] = (float)(stop - start);
  }

  f32x16 acc = {};

  for (int tap = 0; tap < 3; ++tap) {
    for (int ci0 = 0; ci0 < Cin; ci0 += 64) {
      // stage A: 3 planes x 64 co x 64 k
#pragma unroll
      for (int pl = 0; pl < 3; ++pl)
#pragma unroll
        for (int it = 0; it < 2; ++it) {
          int e = it * 256 + tid;
          int row = e >> 3, c8 = e & 7;
          v8s vv = *(const v8s*)&P[(size_t)pl * Cout * K3 + (size_t)(co0 + row) * K3
                                   + tap * Cin + ci0 + c8 * 8];
          *(v8s*)&Al[pl][row * 72 + c8 * 8] = vv;
        }
      // stage B: 3 planes x 64 n x 64 k (shifted row copy, OOB -> 0)
#pragma unroll
      for (int pl = 0; pl < 3; ++pl)
#pragma unroll
        for (int it = 0; it < 2; ++it) {
          int e = it * 256 + tid;
          int n = e >> 3, c8 = e & 7;
          int gn = n0 + n, b = gn >> 6, t = (gn & 63) + tap - 1;
          v8s vv = {};
          if (t >= 0 && t < 64)
            vv = *(const v8s*)&act[(size_t)pl * psIn + ((size_t)(b * 64 + t)) * Cin
                                   + ci0 + c8 * 8];
          *(v8s*)&Bl[pl][n * 72 + c8 * 8] = vv;
        }
      __syncthreads();

      const int abase = (wm * 32 + (l & 31)) * 72 + (l >> 5) * 8;
      const int bbase = (wn * 32 + (l & 31)) * 72 + (l >> 5) * 8;
#pragma unroll
      for (int kk = 0; kk < 4; ++kk) {
        v8s a0 = *(const v8s*)&Al[0][abase + kk * 16];
        v8s a1 = *(const v8s*)&Al[1][abase + kk * 16];
        v8s a2 = *(const v8s*)&Al[2][abase + kk * 16];
        v8s b0 = *(const v8s*)&Bl[0][bbase + kk * 16];
        v8s b1 = *(const v8s*)&Bl[1][bbase + kk * 16];
        v8s b2 = *(const v8s*)&Bl[2][bbase + kk * 16];
        acc = __builtin_amdgcn_mfma_f32_32x32x16_bf16(a0, b0, acc, 0, 0, 0);
        acc = __builtin_amdgcn_mfma_f32_32x32x16_bf16(a0, b1, acc, 0, 0, 0);
        acc = __builtin_amdgcn_mfma_f32_32x32x16_bf16(a1, b0, acc, 0, 0, 0);
        acc = __builtin_amdgcn_mfma_f32_32x32x16_bf16(a1, b1, acc, 0, 0, 0);
        acc = __builtin_amdgcn_mfma_f32_32x32x16_bf16(a0, b2, acc, 0, 0, 0);
        acc = __builtin_amdgcn_mfma_f32_32x32x16_bf16(a2, b0, acc, 0, 0, 0);
      }
      __syncthreads();
    }
  }

  // epilogue: C/D layout col=lane&31, row=(r&3)+8*(r>>2)+4*(lane>>5)
  const int ncol = wn * 32 + (l & 31);
  const int gn = n0 + ncol, b = gn >> 6, t = gn & 63;
  const int hi4 = 4 * (l >> 5);
#pragma unroll
  for (int q4 = 0; q4 < 4; ++q4) {
    int co = co0 + wm * 32 + q4 * 8 + hi4;
    float4 bia = *(const float4*)&Bs[co];
    const float* bp = &bia.x;
    float z[4];
#pragma unroll
    for (int j = 0; j < 4; ++j) z[j] = acc[q4 * 4 + j] + bp[j];
    if (actk == ACT_LRELU) {
      v4s h4, l4, q4v;
#pragma unroll
      for (int j = 0; j < 4; ++j) {
        float zz = lrelu(z[j]);
        short h, lo, qq; split3(zz, h, lo, qq);
        h4[j] = h; l4[j] = lo; q4v[j] = qq;
      }
      size_t o = ((size_t)(b * 64) + t) * Cout + co;
      *(v4s*)&sout[0 * (size_t)psOut + o] = h4;
      *(v4s*)&sout[1 * (size_t)psOut + o] = l4;
      *(v4s*)&sout[2 * (size_t)psOut + o] = q4v;
    } else if (actk == ACT_SIGMAP) {
#pragma unroll
      for (int j = 0; j < 4; ++j) {
        float f = bandS[0][co + j] + bandS[1][co + j] / (1.f + expf(-z[j]));
        fout[((size_t)(b * 128) + co + j) * 64 + t] = f;
      }
    } else {
#pragma unroll
      for (int j = 0; j < 4; ++j)
        fout[((size_t)(b * 128) + co + j) * 64 + t] = z[j] * z[j];
    }
  }
}

// -------------------------------------------------------------------------
// fold_weights: k=7 + nearest-x2 -> 4-tap parity weights, hi/lo bf16,
// tap-major K: Ag[(par*2+pl)*512+co][q*Cin+ci].
// -------------------------------------------------------------------------
__global__ void __launch_bounds__(256) fold_weights(
    const float* __restrict__ W, short* __restrict__ Ag, int Cin)
{
  int idx = blockIdx.x * 256 + threadIdx.x;
  if (idx >= 512 * Cin) return;
  int co = idx / Cin, ci = idx - co * Cin;
  const float* wp = W + (size_t)idx * 7;
  float f[2][4] = {{wp[0],         wp[1] + wp[2], wp[3] + wp[4], wp[5] + wp[6]},
                   {wp[0] + wp[1], wp[2] + wp[3], wp[4] + wp[5], wp[6]}};
  const int K = Cin * 4;
#pragma unroll
  for (int par = 0; par < 2; ++par)
#pragma unroll
    for (int q = 0; q < 4; ++q) {
      float v = f[par][q];
      short h = bf16rne(v);
      short lo = bf16rne(v - bf16tof(h));
      Ag[((size_t)((par * 2 + 0) * 512 + co)) * K + q * Cin + ci] = h;
      Ag[((size_t)((par * 2 + 1) * 512 + co)) * K + q * Cin + ci] = lo;
    }
}

// -------------------------------------------------------------------------
// Noise conv: 2-plane split-bf16 MFMA GEMM (hh,hl,lh), 32x32x16.
//   M=512(co) per parity, K=4*Cin tap-major, N=s per b.
// BM=128, BN=BNS, BK=64; 4 waves (2x2); wave tile 64 x BNS/2.
// LAST: write fp32 [b][co][2s+par] for conv_nl; else bf16 2-plane
// [pl][b][t][512] for the next layer.
// -------------------------------------------------------------------------
template<int BNS, bool LAST>
__global__ void __launch_bounds__(256) conv_noise(
    const short* __restrict__ actIn, const short* __restrict__ Ag,
    const float* __restrict__ Bs, float* __restrict__ foutLast,
    short* __restrict__ actOut, int Cin, int Sin, int psIn, int psOut)
{
  constexpr int NF = BNS / 64;          // n-frags per wave
  const int stiles = Sin / BNS;
  const int nblk = 8 * 16 * stiles;
  const int Q = nblk >> 3;
  int d = blockIdx.x;
  int idx = (d & 7) * Q + (d >> 3);
  int mt  = idx & 3;
  int par = (idx >> 2) & 1;
  int rest = idx >> 3;
  int st = rest % stiles;
  int b  = rest / stiles;

  const int co0 = mt * 128;
  const int s0  = st * BNS;
  const int soff = par ? -1 : -2;

  const int tid = threadIdx.x;
  const int w = tid >> 6, wm = w & 1, wn = w >> 1;
  const int l = tid & 63;

  __shared__ __align__(16) short Al[2][128 * 72];
  __shared__ __align__(16) short Bl[2][BNS * 72];

  f32x16 acc[2][NF] = {};

  for (int q = 0; q < 4; ++q) {
    for (int ci0 = 0; ci0 < Cin; ci0 += 64) {
      // stage A: 2 planes x 128 co x 64 k
#pragma unroll
      for (int pl = 0; pl < 2; ++pl)
#pragma unroll
        for (int it = 0; it < 4; ++it) {
          int e = it * 256 + tid;
          int row = e >> 3, c8 = e & 7;
          v8s vv = *(const v8s*)&Ag[((size_t)((par * 2 + pl) * 512 + co0 + row)) * (Cin * 4)
                                    + q * Cin + ci0 + c8 * 8];
          *(v8s*)&Al[pl][row * 72 + c8 * 8] = vv;
        }
      // stage B: 2 planes x BNS rows x 64 k (shifted copy, OOB -> 0)
#pragma unroll
      for (int pl = 0; pl < 2; ++pl)
#pragma unroll
        for (int it = 0; it < BNS / 32; ++it) {
          int e = it * 256 + tid;
          int n = e >> 3, c8 = e & 7;
          int srow = s0 + n + q + soff;
          v8s vv = {};
          if (srow >= 0 && srow < Sin)
            vv = *(const v8s*)&actIn[(size_t)pl * psIn + ((size_t)(b * Sin + srow)) * Cin
                                     + ci0 + c8 * 8];
          *(v8s*)&Bl[pl][n * 72 + c8 * 8] = vv;
        }
      __syncthreads();

      const int lr = l & 31, lh = (l >> 5) * 8;
#pragma unroll
      for (int kk = 0; kk < 4; ++kk) {
        v8s ah[2], al[2], bh[NF], bl[NF];
#pragma unroll
        for (int fm = 0; fm < 2; ++fm) {
          int ab = (wm * 64 + fm * 32 + lr) * 72 + kk * 16 + lh;
          ah[fm] = *(const v8s*)&Al[0][ab];
          al[fm] = *(const v8s*)&Al[1][ab];
        }
#pragma unroll
        for (int fn = 0; fn < NF; ++fn) {
          int bb = (wn * (BNS / 2) + fn * 32 + lr) * 72 + kk * 16 + lh;
          bh[fn] = *(const v8s*)&Bl[0][bb];
          bl[fn] = *(const v8s*)&Bl[1][bb];
        }
#pragma unroll
        for (int fm = 0; fm < 2; ++fm)
#pragma unroll
          for (int fn = 0; fn < NF; ++fn) {
            acc[fm][fn] = __builtin_amdgcn_mfma_f32_32x32x16_bf16(ah[fm], bh[fn], acc[fm][fn], 0, 0, 0);
            acc[fm][fn] = __builtin_amdgcn_mfma_f32_32x32x16_bf16(ah[fm], bl[fn], acc[fm][fn], 0, 0, 0);
            acc[fm][fn] = __builtin_amdgcn_mfma_f32_32x32x16_bf16(al[fm], bh[fn], acc[fm][fn], 0, 0, 0);
          }
      }
      __syncthreads();
    }
  }

  // epilogue
  const int hi4 = 4 * (l >> 5);
  const int T2 = 2 * Sin;
#pragma unroll
  for (int fm = 0; fm < 2; ++fm)
#pragma unroll
    for (int q4 = 0; q4 < 4; ++q4) {
      int co = co0 + wm * 64 + fm * 32 + q4 * 8 + hi4;
      float4 bia = *(const float4*)&Bs[co];
      const float* bp = &bia.x;
#pragma unroll
      for (int fn = 0; fn < NF; ++fn) {
        int s_l = wn * (BNS / 2) + fn * 32 + (l & 31);
        int t = 2 * (s0 + s_l) + par;
        if (LAST) {
#pragma unroll
          for (int j = 0; j < 4; ++j) {
            float z = lrelu(acc[fm][fn][q4 * 4 + j] + bp[j]);
            foutLast[((size_t)(b * 512) + co + j) * T2 + t] = z;
          }
        } else {
          v4s h4, l4;
#pragma unroll
          for (int j = 0; j < 4; ++j) {
            float z = lrelu(acc[fm][fn][q4 * 4 + j] + bp[j]);
            short h = bf16rne(z);
            h4[j] = h;
            l4[j] = bf16rne(z - bf16tof(h));
          }
          size_t o = ((size_t)(b * T2) + t) * 512 + co;
          *(v4s*)&actOut[0 * (size_t)psOut + o] = h4;
          *(v4s*)&actOut[1 * (size_t)psOut + o] = l4;
        }
      }
    }
}

// -------------------------------------------------------------------------
// Final noise conv: 512 -> 17 channels, k=3 pad=1, T=1024, output squared.
// -------------------------------------------------------------------------
__global__ void __launch_bounds__(256) conv_nl(
    const float* __restrict__ in, const float* __restrict__ W,
    const float* __restrict__ Bs, float* __restrict__ out)
{
  const int t0  = blockIdx.x * 64;
  const int b   = blockIdx.y;
  const int tid = threadIdx.x;
  const int tx  = tid & 15;
  const int cog = tid >> 4;

  __shared__ __align__(16) float inS[64][68];
  __shared__ float wS[64][52];

  float acc0[4] = {}, acc1[4] = {};
  const bool has2 = (cog == 0);

  for (int ci0 = 0; ci0 < 512; ci0 += 64) {
    for (int e = tid; e < 64 * 66; e += 256) {
      int ci = e / 66, u = e - ci * 66;
      int tin = t0 - 1 + u;
      float v = 0.f;
      if (tin >= 0 && tin < 1024) v = in[(size_t)(b * 512 + ci0 + ci) * 1024 + tin];
      inS[ci][u] = v;
    }
    for (int e = tid; e < 64 * 17; e += 256) {
      int col = e / 64, ci = e & 63;
      const float* wp = W + ((size_t)col * 512 + (ci0 + ci)) * 3;
      wS[ci][col * 3 + 0] = wp[0];
      wS[ci][col * 3 + 1] = wp[1];
      wS[ci][col * 3 + 2] = wp[2];
    }
    __syncthreads();
    for (int ci = 0; ci < 64; ++ci) {
      const float4* ip = reinterpret_cast<const float4*>(&inS[ci][tx * 4]);
      float4 i03 = ip[0];
      float2 i45 = *reinterpret_cast<const float2*>(&inS[ci][tx * 4 + 4]);
      float iv[6] = {i03.x, i03.y, i03.z, i03.w, i45.x, i45.y};
      float wA0 = wS[ci][cog * 3], wA1 = wS[ci][cog * 3 + 1], wA2 = wS[ci][cog * 3 + 2];
#pragma unroll
      for (int tt = 0; tt < 4; ++tt)
        acc0[tt] += wA0 * iv[tt] + wA1 * iv[tt + 1] + wA2 * iv[tt + 2];
      if (has2) {
        float wB0 = wS[ci][48], wB1 = wS[ci][49], wB2 = wS[ci][50];
#pragma unroll
        for (int tt = 0; tt < 4; ++tt)
          acc1[tt] += wB0 * iv[tt] + wB1 * iv[tt + 1] + wB2 * iv[tt + 2];
      }
    }
    __syncthreads();
  }

  {
    float bi = Bs[cog];
#pragma unroll
    for (int tt = 0; tt < 4; ++tt) {
      float z = acc0[tt] + bi;
      out[(size_t)(b * 17 + cog) * 1024 + t0 + tx * 4 + tt] = z * z;
    }
    if (has2) {
      float bi2 = Bs[16];
#pragma unroll
      for (int tt = 0; tt < 4; ++tt) {
        float z = acc1[tt] + bi2;
        out[(size_t)(b * 17 + 16) * 1024 + t0 + tx * 4 + tt] = z * z;
      }
    }
  }
}

// -------------------------------------------------------------------------
// Noise bank: per 32-sample frame, 17-bin real DFT * mags, inverse, store.
// -------------------------------------------------------------------------
__global__ void __launch_bounds__(64) noise_filter(
    const float* __restrict__ noise, const float* __restrict__ mags,
    float* __restrict__ filt)
{
  __shared__ float ct[32], st[32];
  int tid = threadIdx.x;
  if (tid < 32) {
    double a = (double)tid * (3.14159265358979323846 / 16.0);
    ct[tid] = (float)cos(a);
    st[tid] = (float)sin(a);
  }
  __syncthreads();

  int fidx = blockIdx.x * 64 + tid;
  int b = fidx >> 10, i = fidx & 1023;

  float xv[32];
#pragma unroll
  for (int n = 0; n < 32; ++n) {
    int idx = i * 16 + n;
    xv[n] = (idx < 16384) ? noise[(size_t)b * 16384 + idx] : 0.f;
  }

  float Yr[17], Yi[17];
#pragma unroll
  for (int k = 0; k <= 16; ++k) {
    float xr = 0.f, xi = 0.f;
    int kk = 0;
#pragma unroll
    for (int n = 0; n < 32; ++n) {
      xr += xv[n] * ct[kk];
      xi -= xv[n] * st[kk];
      kk = (kk + k) & 31;
    }
    float m = mags[((size_t)b * 17 + k) * 1024 + i];
    Yr[k] = xr * m;
    Yi[k] = xi * m;
  }

  float* fo = filt + ((size_t)b * 1024 + i) * 32;
#pragma unroll
  for (int n = 0; n < 32; ++n) {
    float v = Yr[0] + ((n & 1) ? -Yr[16] : Yr[16]);
    int kk = n;
#pragma unroll
    for (int k = 1; k <= 15; ++k) {
      v += 2.f * (Yr[k] * ct[kk] - Yi[k] * st[kk]);
      kk = (kk + n) & 31;
    }
    fo[n] = v * (1.f / 32.f);
  }
}

// -------------------------------------------------------------------------
// Oscillator bank (3-point lerp endpoints + f64 chunk base + f32 Kahan).
// -------------------------------------------------------------------------
static __device__ __forceinline__ int clamp64(int i) { return i < 0 ? 0 : (i > 63 ? 63 : i); }

__global__ void __launch_bounds__(256) osc_phase(
    const float* __restrict__ fsm, double* __restrict__ phaseBase)
{
  const int o = blockIdx.x, b = blockIdx.y;
  const float* frow = fsm + (size_t)(b * 128 + o) * 64;
  const int c = threadIdx.x;

  const float ic0 = ((float)(c * 64) - 127.5f) * (1.0f / 256.0f);
  const int ilo = (int)floorf(ic0);
  float f0 = frow[clamp64(ilo)], f1 = frow[clamp64(ilo + 1)], f2 = frow[clamp64(ilo + 2)];

  double local = 0.0;
#pragma unroll 8
  for (int j = 0; j < 64; ++j) {
    float ic = ic0 + (float)j * (1.0f / 256.0f);
    float fl = floorf(ic);
    float w  = ic - fl;
    bool hi = ((int)fl) > ilo;
    float fa = hi ? f1 : f0;
    float fb = hi ? f2 : f1;
    float f = fa * (1.f - w) + fb * w;
    f = fminf(fmaxf(f, 20.f), 11025.f);
    local += (double)f;
  }
  local *= (1.0 / 22050.0);

  __shared__ double ps[256];
  ps[c] = local;
  __syncthreads();
  for (int off = 1; off < 256; off <<= 1) {
    double v = (c >= off) ? ps[c - off] : 0.0;
    __syncthreads();
    ps[c] += v;
    __syncthreads();
  }
  phaseBase[(size_t)(b * 128 + o) * 256 + c] = ps[c] - local;
}

__global__ void __launch_bounds__(128) osc_sum(
    const float* __restrict__ fsm, const float* __restrict__ lsm,
    const double* __restrict__ phaseBase, const float* __restrict__ filt,
    float* __restrict__ out)
{
  const int c = blockIdx.x, b = blockIdx.y;
  const int tid = threadIdx.x;
  __shared__ float contrib[128][65];
  __shared__ float part[2][64];
  const int o = tid;
  const float* frow = fsm + (size_t)(b * 128 + o) * 64;
  const float* arow = lsm + (size_t)(b * 128 + o) * 64;

  double pb = phaseBase[(size_t)(b * 128 + o) * 256 + c];
  float fb0 = (float)(pb - floor(pb));

  const float ic0 = ((float)(c * 64) - 127.5f) * (1.0f / 256.0f);
  const int ilo = (int)floorf(ic0);
  float f0 = frow[clamp64(ilo)], f1 = frow[clamp64(ilo + 1)], f2 = frow[clamp64(ilo + 2)];
  float a0 = arow[clamp64(ilo)], a1 = arow[clamp64(ilo + 1)], a2 = arow[clamp64(ilo + 2)];

  float rel = 0.f, comp = 0.f;
#pragma unroll 8
  for (int j = 0; j < 64; ++j) {
    float ic = ic0 + (float)j * (1.0f / 256.0f);
    float fl = floorf(ic);
    float w  = ic - fl;
    bool hi = ((int)fl) > ilo;
    float fa = hi ? f1 : f0;
    float fb = hi ? f2 : f1;
    float f = fa * (1.f - w) + fb * w;
    f = fminf(fmaxf(f, 20.f), 11025.f);
    float y = f * (1.0f / 22050.0f) - comp;
    float t = rel + y;
    comp = (t - rel) - y;
    rel = t;
    float tot = fb0 + rel;
    float frac = tot - floorf(tot);
    float s = sinpif(2.f * frac);
    float aa = hi ? a1 : a0;
    float ab = hi ? a2 : a1;
    float am = aa * (1.f - w) + ab * w;
    contrib[o][j] = s * am;
  }
  __syncthreads();
  int half = tid >> 6, tl = tid & 63;
  float sum = 0.f;
  for (int oo = 0; oo < 64; ++oo) sum += contrib[half * 64 + oo][tl];
  part[half][tl] = sum;
  __syncthreads();
  if (tid < 64) {
    int t = c * 64 + tid;
    float v = part[0][tid] + part[1][tid];
    int i0 = t >> 4, r = t & 15;
    v += filt[((size_t)(b << 10) + i0) * 32 + r];
    if (i0 > 0) v += filt[((size_t)(b << 10) + i0 - 1) * 32 + 16 + r];
    out[(size_t)b * 16384 + t] = v;
  }
}

// -------------------------------------------------------------------------
extern "C" void kernel_launch(void* const* d_in, const int* in_sizes, int n_in,
                              void* d_out, int out_size, void* d_ws, size_t ws_size,
                              hipStream_t stream)
{
  (void)in_sizes; (void)n_in; (void)out_size; (void)ws_size;

  const float* x     = (const float*)d_in[0];
  const float* noise = (const float*)d_in[1];
  const float* mw0 = (const float*)d_in[2];  const float* mb0 = (const float*)d_in[3];
  const float* mw1 = (const float*)d_in[4];  const float* mb1 = (const float*)d_in[5];
  const float* mw2 = (const float*)d_in[6];  const float* mb2 = (const float*)d_in[7];
  const float* mw3 = (const float*)d_in[8];  const float* mb3 = (const float*)d_in[9];
  const float* fw  = (const float*)d_in[10]; const float* fb  = (const float*)d_in[11];
  const float* gw0 = (const float*)d_in[12]; const float* gb0 = (const float*)d_in[13];
  const float* gw1 = (const float*)d_in[14]; const float* gb1 = (const float*)d_in[15];
  const float* gw2 = (const float*)d_in[16]; const float* gb2 = (const float*)d_in[17];
  const float* gw3 = (const float*)d_in[18]; const float* gb3 = (const float*)d_in[19];
  const float* lw  = (const float*)d_in[20]; const float* lb  = (const float*)d_in[21];
  const float* nw0 = (const float*)d_in[22]; const float* nb0 = (const float*)d_in[23];
  const float* nw1 = (const float*)d_in[24]; const float* nb1 = (const float*)d_in[25];
  const float* nw2 = (const float*)d_in[26]; const float* nb2 = (const float*)d_in[27];
  const float* nw3 = (const float*)d_in[28]; const float* nb3 = (const float*)d_in[29];
  const float* nlw = (const float*)d_in[30]; const float* nlb = (const float*)d_in[31];

  float* ws = (float*)d_ws;
  // ---- workspace (float offsets; high-water 14,942,208 fl = 59.8 MB) ----
  // R0 [0, 8,388,608): m/g phase {gP, hm0/1, hg0/1, xm3}; then l2out; then l4out
  short*  gP   = (short*)(ws + 0);          // 8,257,536 sh
  short*  hm0  = (short*)(ws + 4128768);    // 3-plane acts [pl][b][64][512]
  short*  hm1  = (short*)(ws + 4915200);
  short*  hg0  = (short*)(ws + 5701632);
  short*  hg1  = (short*)(ws + 6488064);
  short*  xm3  = (short*)(ws + 7274496);    // [3][16][64][128]
  short*  l2out = (short*)(ws + 0);         // [2][16][256][512]
  float*  l4out = ws + 0;                   // fp32 [16][512][1024]
  // R1 [8,388,608, 12,582,912): mP; then l1out/l3out; then nl+filt
  short*  mP   = (short*)(ws + 8388608);    // 8,257,536 sh
  short*  l1out = (short*)(ws + 8388608);   // [2][16][128][512]
  short*  l3out = (short*)(ws + 8388608);   // [2][16][512][512]
  float*  nl   = ws + 8388608;              // [16][17][1024]
  float*  filt = ws + 8667136;              // [16][1024][32]
  // R3 [12,582,912, 14,680,064): noise panel; then phaseBase
  short*  E    = (short*)(ws + 12582912);   // up to 4,194,304 sh
  double* phaseBase = (double*)(ws + 12582912);  // [16][128][256]
  // R4
  float*  fsm  = ws + 14680064;             // [16][128][64]
  float*  lsm  = ws + 14811136;

  float* out = (float*)d_out;

  const int PS_X = 131072;   // xm3 plane stride (shorts)
  const int PS_H = 524288;   // m/g act plane stride

  // ---- prep ----
  prep_acts<<<512, 256, 0, stream>>>(x, xm3);
  prep_panels<<<7168, 256, 0, stream>>>(mw0, mw1, mw2, mw3, fw,
                                        gw0, gw1, gw2, gw3, lw, mP, gP);

  // ---- m/g paths: 3-plane split-bf16 32x32x16 MFMA convs ----
  conv_path<<<256, 256, 0, stream>>>(xm3, xm3, mP + 0, gP + 0, mb0, gb0,
      nullptr, nullptr, hm0, hg0, 128, 512, PS_X, PS_H, ACT_LRELU, ACT_LRELU);
  conv_path<<<256, 256, 0, stream>>>(hm0, hg0, mP + 589824, gP + 589824, mb1, gb1,
      nullptr, nullptr, hm1, hg1, 512, 512, PS_H, PS_H, ACT_LRELU, ACT_LRELU);
  conv_path<<<256, 256, 0, stream>>>(hm1, hg1, mP + 2949120, gP + 2949120, mb2, gb2,
      nullptr, nullptr, hm0, hg0, 512, 512, PS_H, PS_H, ACT_LRELU, ACT_LRELU);
  conv_path<<<256, 256, 0, stream>>>(hm0, hg0, mP + 5308416, gP + 5308416, mb3, gb3,
      nullptr, nullptr, hm1, hg1, 512, 512, PS_H, PS_H, ACT_LRELU, ACT_LRELU);
  conv_path<<<64, 256, 0, stream>>>(hm1, hg1, mP + 7667712, gP + 7667712, fb, lb,
      fsm, lsm, nullptr, nullptr, 512, 128, PS_H, 0, ACT_SIGMAP, ACT_SQUARE);

  // ---- noise path: 2-plane split-bf16 32x32x16 MFMA convs ----
  fold_weights<<<256, 256, 0, stream>>>(nw0, E, 128);
  conv_noise<64, false><<<128, 256, 0, stream>>>(xm3, E, nb0, nullptr, l1out,
      128, 64, PS_X, 1048576);
  fold_weights<<<1024, 256, 0, stream>>>(nw1, E, 512);
  conv_noise<128, false><<<128, 256, 0, stream>>>(l1out, E, nb1, nullptr, l2out,
      512, 128, 1048576, 2097152);
  fold_weights<<<1024, 256, 0, stream>>>(nw2, E, 512);
  conv_noise<128, false><<<256, 256, 0, stream>>>(l2out, E, nb2, nullptr, l3out,
      512, 256, 2097152, 4194304);
  fold_weights<<<1024, 256, 0, stream>>>(nw3, E, 512);
  conv_noise<128, true><<<512, 256, 0, stream>>>(l3out, E, nb3, l4out, nullptr,
      512, 512, 4194304, 0);

  conv_nl<<<dim3(16, 16), 256, 0, stream>>>(l4out, nlw, nlb, nl);

  // ---- filtered noise frames ----
  noise_filter<<<256, 64, 0, stream>>>(noise, nl, filt);

  // ---- oscillator bank + final sum ----
  osc_phase<<<dim3(128, 16), 256, 0, stream>>>(fsm, phaseBase);
  osc_sum<<<dim3(256, 16), 128, 0, stream>>>(fsm, lsm, phaseBase, filt, out);
}

// Round 7
// 597.115 us; speedup vs baseline: 5.7292x; 1.4059x over previous
//
#include <hip/hip_runtime.h>
#include <math.h>

#define ACT_LRELU  0
#define ACT_SIGMAP 1
#define ACT_SQUARE 2

typedef __attribute__((ext_vector_type(8))) short v8s;
typedef __attribute__((ext_vector_type(4))) short v4s;
typedef __attribute__((ext_vector_type(16))) float f32x16;

static __device__ __forceinline__ float lrelu(float x) { return x >= 0.f ? x : 0.2f * x; }

static __device__ __forceinline__ short bf16rne(float x) {
  unsigned u = __float_as_uint(x);
  unsigned r = (u + 0x7FFFu + ((u >> 16) & 1u)) >> 16;
  return (short)r;
}
static __device__ __forceinline__ float bf16tof(short h) {
  return __uint_as_float(((unsigned)(unsigned short)h) << 16);
}
static __device__ __forceinline__ void split3(float v, short& h, short& l, short& q) {
  h = bf16rne(v); float r1 = v - bf16tof(h);
  l = bf16rne(r1); float r2 = r1 - bf16tof(l);
  q = bf16rne(r2);
}

// -------------------------------------------------------------------------
// prep_acts: x[b][128][64] -> xm3[pl][b][t][ci], 3 bf16 planes (~exact fp32)
// -------------------------------------------------------------------------
__global__ void __launch_bounds__(256) prep_acts(
    const float* __restrict__ x, short* __restrict__ xm3)
{
  int e = blockIdx.x * 256 + threadIdx.x;
  if (e >= 131072) return;
  int b = e >> 13, rem = e & 8191, t = rem >> 7, ci = rem & 127;
  float v = x[((size_t)(b * 128) + ci) * 64 + t];
  short h, l, q; split3(v, h, l, q);
  size_t o = ((size_t)(b * 64) + t) * 128 + ci;
  xm3[0 * 131072 + o] = h;
  xm3[1 * 131072 + o] = l;
  xm3[2 * 131072 + o] = q;
}

// -------------------------------------------------------------------------
// prep_panels: all 5 m/g layers, both paths. W[Cout][Cin][3] ->
// P[pl][co][tap*Cin+ci] (3 bf16 planes, tap-major K).
// -------------------------------------------------------------------------
__global__ void __launch_bounds__(256) prep_panels(
    const float* mw0, const float* mw1, const float* mw2, const float* mw3, const float* fw,
    const float* gw0, const float* gw1, const float* gw2, const float* gw3, const float* lw,
    short* __restrict__ mP, short* __restrict__ gP)
{
  int i = blockIdx.x * 256 + threadIdx.x;
  const int PER_PATH = 917504;
  if (i >= 2 * PER_PATH) return;
  int path = i >= PER_PATH ? 1 : 0;
  int r = i - path * PER_PATH;
  int layer, Cin, Cout; size_t poff;
  if (r < 65536)       { layer = 0;               Cin = 128; Cout = 512; poff = 0; }
  else if (r < 327680) { layer = 1; r -= 65536;   Cin = 512; Cout = 512; poff = 589824; }
  else if (r < 589824) { layer = 2; r -= 327680;  Cin = 512; Cout = 512; poff = 2949120; }
  else if (r < 851968) { layer = 3; r -= 589824;  Cin = 512; Cout = 512; poff = 5308416; }
  else                 { layer = 4; r -= 851968;  Cin = 512; Cout = 128; poff = 7667712; }
  const float* Wm[5] = {mw0, mw1, mw2, mw3, fw};
  const float* Wg[5] = {gw0, gw1, gw2, gw3, lw};
  const float* W = path ? Wg[layer] : Wm[layer];
  short* P = (path ? gP : mP) + poff;
  int co = r / Cin, ci = r - co * Cin;
  const int K3 = 3 * Cin;
  const float* wp = W + (size_t)(co * Cin + ci) * 3;
#pragma unroll
  for (int tap = 0; tap < 3; ++tap) {
    short h, l, q; split3(wp[tap], h, l, q);
    size_t base = (size_t)co * K3 + tap * Cin + ci;
    P[(size_t)0 * Cout * K3 + base] = h;
    P[(size_t)1 * Cout * K3 + base] = l;
    P[(size_t)2 * Cout * K3 + base] = q;
  }
}

// -------------------------------------------------------------------------
// m/g path conv: 3-plane split-bf16 MFMA GEMM, 32x32x16, ~fp32 precision,
// T14 async staging: issue next k-step's global loads before this step's
// MFMA phase; ds_write after the post-read barrier (latency hidden).
// -------------------------------------------------------------------------
__global__ void __launch_bounds__(256, 2) conv_path(
    const short* __restrict__ actM, const short* __restrict__ actG,
    const short* __restrict__ Pm, const short* __restrict__ Pg,
    const float* __restrict__ BsM, const float* __restrict__ BsG,
    float* __restrict__ foutM, float* __restrict__ foutG,
    short* __restrict__ soutM, short* __restrict__ soutG,
    int Cin, int Cout, int psIn, int psOut, int actMk, int actGk)
{
  const int mtiles = Cout >> 6;
  const int nblk = 2 * mtiles * 16;
  const int Q = nblk >> 3;
  int d = blockIdx.x;
  int idx = (d & 7) * Q + (d >> 3);
  int mt = idx % mtiles;
  int tmp = idx / mtiles;
  int nt = tmp & 15;
  int path = tmp >> 4;

  const short* act = path ? actG : actM;
  const short* P   = path ? Pg : Pm;
  const float* Bs  = path ? BsG : BsM;
  float* fout      = path ? foutG : foutM;
  short* sout      = path ? soutG : soutM;
  const int actk   = path ? actGk : actMk;

  const int K3 = 3 * Cin;
  const int co0 = mt * 64;
  const int n0  = nt * 64;
  const int nci = Cin >> 6;
  const int NT  = 3 * nci;

  const int tid = threadIdx.x;
  const int w = tid >> 6, wm = w & 1, wn = w >> 1;
  const int l = tid & 63;

  __shared__ __align__(16) short Al[3][64 * 72];
  __shared__ __align__(16) short Bl[3][64 * 72];
  __shared__ float bandS[2][128];

  if (actk == ACT_SIGMAP && tid < 128) {
    double lg = log(551.25);
    double stop  = 20.0 * exp(lg * (double)tid / 127.0);
    double start = (tid == 0) ? 0.0 : 20.0 * exp(lg * (double)(tid - 1) / 127.0);
    bandS[0][tid] = (float)start;
    bandS[1][tid] = (float)(stop - start);
  }

  f32x16 acc = {};
  v8s rA[3][2], rB[3][2];

  auto LOADA = [&](int t) {
    int tap = t / nci, ci0 = (t % nci) << 6;
#pragma unroll
    for (int pl = 0; pl < 3; ++pl)
#pragma unroll
      for (int it = 0; it < 2; ++it) {
        int e = it * 256 + tid;
        int row = e >> 3, c8 = e & 7;
        rA[pl][it] = *(const v8s*)&P[(size_t)pl * Cout * K3 + (size_t)(co0 + row) * K3
                                     + tap * Cin + ci0 + c8 * 8];
      }
  };
  auto LOADB = [&](int t) {
    int tap = t / nci, ci0 = (t % nci) << 6;
#pragma unroll
    for (int pl = 0; pl < 3; ++pl)
#pragma unroll
      for (int it = 0; it < 2; ++it) {
        int e = it * 256 + tid;
        int n = e >> 3, c8 = e & 7;
        int gn = n0 + n, bb = gn >> 6, trow = (gn & 63) + tap - 1;
        v8s vv = {};
        if (trow >= 0 && trow < 64)
          vv = *(const v8s*)&act[(size_t)pl * psIn + ((size_t)(bb * 64 + trow)) * Cin
                                 + ci0 + c8 * 8];
        rB[pl][it] = vv;
      }
  };
  auto WRITE = [&]() {
#pragma unroll
    for (int pl = 0; pl < 3; ++pl)
#pragma unroll
      for (int it = 0; it < 2; ++it) {
        int e = it * 256 + tid;
        int row = e >> 3, c8 = e & 7;
        *(v8s*)&Al[pl][row * 72 + c8 * 8] = rA[pl][it];
        *(v8s*)&Bl[pl][row * 72 + c8 * 8] = rB[pl][it];
      }
  };

  LOADA(0); LOADB(0);
  WRITE();
  __syncthreads();

  for (int t = 0; t < NT; ++t) {
    if (t + 1 < NT) { LOADA(t + 1); LOADB(t + 1); }
    const int abase = (wm * 32 + (l & 31)) * 72 + (l >> 5) * 8;
    const int bbase = (wn * 32 + (l & 31)) * 72 + (l >> 5) * 8;
#pragma unroll
    for (int kk = 0; kk < 4; ++kk) {
      v8s a0 = *(const v8s*)&Al[0][abase + kk * 16];
      v8s a1 = *(const v8s*)&Al[1][abase + kk * 16];
      v8s a2 = *(const v8s*)&Al[2][abase + kk * 16];
      v8s b0 = *(const v8s*)&Bl[0][bbase + kk * 16];
      v8s b1 = *(const v8s*)&Bl[1][bbase + kk * 16];
      v8s b2 = *(const v8s*)&Bl[2][bbase + kk * 16];
      acc = __builtin_amdgcn_mfma_f32_32x32x16_bf16(a0, b0, acc, 0, 0, 0);
      acc = __builtin_amdgcn_mfma_f32_32x32x16_bf16(a0, b1, acc, 0, 0, 0);
      acc = __builtin_amdgcn_mfma_f32_32x32x16_bf16(a1, b0, acc, 0, 0, 0);
      acc = __builtin_amdgcn_mfma_f32_32x32x16_bf16(a1, b1, acc, 0, 0, 0);
      acc = __builtin_amdgcn_mfma_f32_32x32x16_bf16(a0, b2, acc, 0, 0, 0);
      acc = __builtin_amdgcn_mfma_f32_32x32x16_bf16(a2, b0, acc, 0, 0, 0);
    }
    __syncthreads();
    if (t + 1 < NT) { WRITE(); __syncthreads(); }
  }

  // epilogue: C/D layout col=lane&31, row=(r&3)+8*(r>>2)+4*(lane>>5)
  const int ncol = wn * 32 + (l & 31);
  const int gn = n0 + ncol, bb = gn >> 6, t = gn & 63;
  const int hi4 = 4 * (l >> 5);
#pragma unroll
  for (int q4 = 0; q4 < 4; ++q4) {
    int co = co0 + wm * 32 + q4 * 8 + hi4;
    float4 bia = *(const float4*)&Bs[co];
    const float* bp = &bia.x;
    float z[4];
#pragma unroll
    for (int j = 0; j < 4; ++j) z[j] = acc[q4 * 4 + j] + bp[j];
    if (actk == ACT_LRELU) {
      v4s h4, l4, q4v;
#pragma unroll
      for (int j = 0; j < 4; ++j) {
        float zz = lrelu(z[j]);
        short h, lo, qq; split3(zz, h, lo, qq);
        h4[j] = h; l4[j] = lo; q4v[j] = qq;
      }
      size_t o = ((size_t)(bb * 64) + t) * Cout + co;
      *(v4s*)&sout[0 * (size_t)psOut + o] = h4;
      *(v4s*)&sout[1 * (size_t)psOut + o] = l4;
      *(v4s*)&sout[2 * (size_t)psOut + o] = q4v;
    } else if (actk == ACT_SIGMAP) {
#pragma unroll
      for (int j = 0; j < 4; ++j) {
        float f = bandS[0][co + j] + bandS[1][co + j] / (1.f + expf(-z[j]));
        fout[((size_t)(bb * 128) + co + j) * 64 + t] = f;
      }
    } else {
#pragma unroll
      for (int j = 0; j < 4; ++j)
        fout[((size_t)(bb * 128) + co + j) * 64 + t] = z[j] * z[j];
    }
  }
}

// -------------------------------------------------------------------------
// fold_all: all 4 noise layers at once. k=7 + nearest-x2 -> 4-tap parity
// weights, hi/lo bf16, tap-major K: Ag[(par*2+pl)*512+co][q*Cin+ci].
// Panel sizes (shorts): E1 = 4*512*512 = 1,048,576; E2/3/4 = 4*512*2048
// = 4,194,304 each (8,388,608 BYTES — the round-5 layout undersized these).
// -------------------------------------------------------------------------
__global__ void __launch_bounds__(256) fold_all(
    const float* __restrict__ nw0, const float* __restrict__ nw1,
    const float* __restrict__ nw2, const float* __restrict__ nw3,
    short* __restrict__ E1, short* __restrict__ E2,
    short* __restrict__ E3, short* __restrict__ E4)
{
  int i = blockIdx.x * 256 + threadIdx.x;
  const float* W; short* Ag; int Cin; int idx;
  if (i < 65536)        { W = nw0; Ag = E1; Cin = 128; idx = i; }
  else if (i < 327680)  { W = nw1; Ag = E2; Cin = 512; idx = i - 65536; }
  else if (i < 589824)  { W = nw2; Ag = E3; Cin = 512; idx = i - 327680; }
  else if (i < 851968)  { W = nw3; Ag = E4; Cin = 512; idx = i - 589824; }
  else return;
  int co = idx / Cin, ci = idx - co * Cin;
  const float* wp = W + (size_t)idx * 7;
  float f[2][4] = {{wp[0],         wp[1] + wp[2], wp[3] + wp[4], wp[5] + wp[6]},
                   {wp[0] + wp[1], wp[2] + wp[3], wp[4] + wp[5], wp[6]}};
  const int K = Cin * 4;
#pragma unroll
  for (int par = 0; par < 2; ++par)
#pragma unroll
    for (int q = 0; q < 4; ++q) {
      float v = f[par][q];
      short h = bf16rne(v);
      short lo = bf16rne(v - bf16tof(h));
      Ag[((size_t)((par * 2 + 0) * 512 + co)) * K + q * Cin + ci] = h;
      Ag[((size_t)((par * 2 + 1) * 512 + co)) * K + q * Cin + ci] = lo;
    }
}

// -------------------------------------------------------------------------
// Noise conv: 2-plane split-bf16 MFMA GEMM (hh,hl,lh), 32x32x16, T14 async.
//   M=512(co) per parity, K=4*CIN tap-major, N=s per b.
// BM=MF*64, BN=BNS, BK=64; 4 waves (2x2).
// -------------------------------------------------------------------------
template<int MF, int BNS, int CIN, bool LAST>
__global__ void __launch_bounds__(256, 2) conv_noise(
    const short* __restrict__ actIn, const short* __restrict__ Ag,
    const float* __restrict__ Bs, float* __restrict__ foutLast,
    short* __restrict__ actOut, int Sin, int psIn, int psOut)
{
  constexpr int NF   = BNS / 64;
  constexpr int BM   = MF * 64;
  constexpr int AITS = BM / 32;
  constexpr int BITS = BNS / 32;
  constexpr int K    = CIN * 4;
  constexpr int nci  = CIN / 64;
  constexpr int NT   = 4 * nci;
  const int mtiles = 512 / BM;
  const int stiles = Sin / BNS;
  const int nblk = mtiles * 2 * 16 * stiles;
  const int Q = nblk >> 3;
  int d = blockIdx.x;
  int idx = (d & 7) * Q + (d >> 3);
  int mt = idx % mtiles;
  int t1 = idx / mtiles;
  int par = t1 & 1;
  int rest = t1 >> 1;
  int st = rest % stiles;
  int b = rest / stiles;

  const int co0 = mt * BM;
  const int s0 = st * BNS;
  const int soff = par ? -1 : -2;

  const int tid = threadIdx.x;
  const int w = tid >> 6, wm = w & 1, wn = w >> 1;
  const int l = tid & 63;

  __shared__ __align__(16) short Al[2][BM * 72];
  __shared__ __align__(16) short Bl[2][BNS * 72];

  f32x16 acc[MF][NF] = {};
  v8s rA[2][AITS], rB[2][BITS];

  auto LOADA = [&](int t) {
    int q = t / nci, ci0 = (t % nci) << 6;
#pragma unroll
    for (int pl = 0; pl < 2; ++pl)
#pragma unroll
      for (int it = 0; it < AITS; ++it) {
        int e = it * 256 + tid;
        int row = e >> 3, c8 = e & 7;
        rA[pl][it] = *(const v8s*)&Ag[((size_t)((par * 2 + pl) * 512 + co0 + row)) * K
                                      + q * CIN + ci0 + c8 * 8];
      }
  };
  auto LOADB = [&](int t) {
    int q = t / nci, ci0 = (t % nci) << 6;
#pragma unroll
    for (int pl = 0; pl < 2; ++pl)
#pragma unroll
      for (int it = 0; it < BITS; ++it) {
        int e = it * 256 + tid;
        int n = e >> 3, c8 = e & 7;
        int srow = s0 + n + q + soff;
        v8s vv = {};
        if (srow >= 0 && srow < Sin)
          vv = *(const v8s*)&actIn[(size_t)pl * psIn + ((size_t)(b * Sin + srow)) * CIN
                                   + ci0 + c8 * 8];
        rB[pl][it] = vv;
      }
  };
  auto WRITE = [&]() {
#pragma unroll
    for (int pl = 0; pl < 2; ++pl) {
#pragma unroll
      for (int it = 0; it < AITS; ++it) {
        int e = it * 256 + tid;
        *(v8s*)&Al[pl][(e >> 3) * 72 + (e & 7) * 8] = rA[pl][it];
      }
#pragma unroll
      for (int it = 0; it < BITS; ++it) {
        int e = it * 256 + tid;
        *(v8s*)&Bl[pl][(e >> 3) * 72 + (e & 7) * 8] = rB[pl][it];
      }
    }
  };

  LOADA(0); LOADB(0);
  WRITE();
  __syncthreads();

  for (int t = 0; t < NT; ++t) {
    if (t + 1 < NT) { LOADA(t + 1); LOADB(t + 1); }
    const int lr = l & 31, lh = (l >> 5) * 8;
#pragma unroll
    for (int kk = 0; kk < 4; ++kk) {
      v8s ah[MF], al[MF], bh[NF], bl[NF];
#pragma unroll
      for (int fm = 0; fm < MF; ++fm) {
        int ab = (wm * (MF * 32) + fm * 32 + lr) * 72 + kk * 16 + lh;
        ah[fm] = *(const v8s*)&Al[0][ab];
        al[fm] = *(const v8s*)&Al[1][ab];
      }
#pragma unroll
      for (int fn = 0; fn < NF; ++fn) {
        int bb = (wn * (BNS / 2) + fn * 32 + lr) * 72 + kk * 16 + lh;
        bh[fn] = *(const v8s*)&Bl[0][bb];
        bl[fn] = *(const v8s*)&Bl[1][bb];
      }
#pragma unroll
      for (int fm = 0; fm < MF; ++fm)
#pragma unroll
        for (int fn = 0; fn < NF; ++fn) {
          acc[fm][fn] = __builtin_amdgcn_mfma_f32_32x32x16_bf16(ah[fm], bh[fn], acc[fm][fn], 0, 0, 0);
          acc[fm][fn] = __builtin_amdgcn_mfma_f32_32x32x16_bf16(ah[fm], bl[fn], acc[fm][fn], 0, 0, 0);
          acc[fm][fn] = __builtin_amdgcn_mfma_f32_32x32x16_bf16(al[fm], bh[fn], acc[fm][fn], 0, 0, 0);
        }
    }
    __syncthreads();
    if (t + 1 < NT) { WRITE(); __syncthreads(); }
  }

  // epilogue
  const int hi4 = 4 * (l >> 5);
  const int T2 = 2 * Sin;
#pragma unroll
  for (int fm = 0; fm < MF; ++fm)
#pragma unroll
    for (int q4 = 0; q4 < 4; ++q4) {
      int co = co0 + wm * (MF * 32) + fm * 32 + q4 * 8 + hi4;
      float4 bia = *(const float4*)&Bs[co];
      const float* bp = &bia.x;
#pragma unroll
      for (int fn = 0; fn < NF; ++fn) {
        int s_l = wn * (BNS / 2) + fn * 32 + (l & 31);
        int t = 2 * (s0 + s_l) + par;
        if (LAST) {
#pragma unroll
          for (int j = 0; j < 4; ++j) {
            float z = lrelu(acc[fm][fn][q4 * 4 + j] + bp[j]);
            foutLast[((size_t)(b * 512) + co + j) * T2 + t] = z;
          }
        } else {
          v4s h4, l4;
#pragma unroll
          for (int j = 0; j < 4; ++j) {
            float z = lrelu(acc[fm][fn][q4 * 4 + j] + bp[j]);
            short h = bf16rne(z);
            h4[j] = h;
            l4[j] = bf16rne(z - bf16tof(h));
          }
          size_t o = ((size_t)(b * T2) + t) * 512 + co;
          *(v4s*)&actOut[0 * (size_t)psOut + o] = h4;
          *(v4s*)&actOut[1 * (size_t)psOut + o] = l4;
        }
      }
    }
}

// -------------------------------------------------------------------------
// Final noise conv: 512 -> 17 channels, k=3 pad=1, T=1024, output squared.
// -------------------------------------------------------------------------
__global__ void __launch_bounds__(256) conv_nl(
    const float* __restrict__ in, const float* __restrict__ W,
    const float* __restrict__ Bs, float* __restrict__ out)
{
  const int t0  = blockIdx.x * 64;
  const int b   = blockIdx.y;
  const int tid = threadIdx.x;
  const int tx  = tid & 15;
  const int cog = tid >> 4;

  __shared__ __align__(16) float inS[64][68];
  __shared__ float wS[64][52];

  float acc0[4] = {}, acc1[4] = {};
  const bool has2 = (cog == 0);

  for (int ci0 = 0; ci0 < 512; ci0 += 64) {
    for (int e = tid; e < 64 * 66; e += 256) {
      int ci = e / 66, u = e - ci * 66;
      int tin = t0 - 1 + u;
      float v = 0.f;
      if (tin >= 0 && tin < 1024) v = in[(size_t)(b * 512 + ci0 + ci) * 1024 + tin];
      inS[ci][u] = v;
    }
    for (int e = tid; e < 64 * 17; e += 256) {
      int col = e / 64, ci = e & 63;
      const float* wp = W + ((size_t)col * 512 + (ci0 + ci)) * 3;
      wS[ci][col * 3 + 0] = wp[0];
      wS[ci][col * 3 + 1] = wp[1];
      wS[ci][col * 3 + 2] = wp[2];
    }
    __syncthreads();
    for (int ci = 0; ci < 64; ++ci) {
      const float4* ip = reinterpret_cast<const float4*>(&inS[ci][tx * 4]);
      float4 i03 = ip[0];
      float2 i45 = *reinterpret_cast<const float2*>(&inS[ci][tx * 4 + 4]);
      float iv[6] = {i03.x, i03.y, i03.z, i03.w, i45.x, i45.y};
      float wA0 = wS[ci][cog * 3], wA1 = wS[ci][cog * 3 + 1], wA2 = wS[ci][cog * 3 + 2];
#pragma unroll
      for (int tt = 0; tt < 4; ++tt)
        acc0[tt] += wA0 * iv[tt] + wA1 * iv[tt + 1] + wA2 * iv[tt + 2];
      if (has2) {
        float wB0 = wS[ci][48], wB1 = wS[ci][49], wB2 = wS[ci][50];
#pragma unroll
        for (int tt = 0; tt < 4; ++tt)
          acc1[tt] += wB0 * iv[tt] + wB1 * iv[tt + 1] + wB2 * iv[tt + 2];
      }
    }
    __syncthreads();
  }

  {
    float bi = Bs[cog];
#pragma unroll
    for (int tt = 0; tt < 4; ++tt) {
      float z = acc0[tt] + bi;
      out[(size_t)(b * 17 + cog) * 1024 + t0 + tx * 4 + tt] = z * z;
    }
    if (has2) {
      float bi2 = Bs[16];
#pragma unroll
      for (int tt = 0; tt < 4; ++tt) {
        float z = acc1[tt] + bi2;
        out[(size_t)(b * 17 + 16) * 1024 + t0 + tx * 4 + tt] = z * z;
      }
    }
  }
}

// -------------------------------------------------------------------------
// Noise bank: per 32-sample frame, 17-bin real DFT * mags, inverse, store.
// -------------------------------------------------------------------------
__global__ void __launch_bounds__(64) noise_filter(
    const float* __restrict__ noise, const float* __restrict__ mags,
    float* __restrict__ filt)
{
  __shared__ float ct[32], st[32];
  int tid = threadIdx.x;
  if (tid < 32) {
    double a = (double)tid * (3.14159265358979323846 / 16.0);
    ct[tid] = (float)cos(a);
    st[tid] = (float)sin(a);
  }
  __syncthreads();

  int fidx = blockIdx.x * 64 + tid;
  int b = fidx >> 10, i = fidx & 1023;

  float xv[32];
#pragma unroll
  for (int n = 0; n < 32; ++n) {
    int idx = i * 16 + n;
    xv[n] = (idx < 16384) ? noise[(size_t)b * 16384 + idx] : 0.f;
  }

  float Yr[17], Yi[17];
#pragma unroll
  for (int k = 0; k <= 16; ++k) {
    float xr = 0.f, xi = 0.f;
    int kk = 0;
#pragma unroll
    for (int n = 0; n < 32; ++n) {
      xr += xv[n] * ct[kk];
      xi -= xv[n] * st[kk];
      kk = (kk + k) & 31;
    }
    float m = mags[((size_t)b * 17 + k) * 1024 + i];
    Yr[k] = xr * m;
    Yi[k] = xi * m;
  }

  float* fo = filt + ((size_t)b * 1024 + i) * 32;
#pragma unroll
  for (int n = 0; n < 32; ++n) {
    float v = Yr[0] + ((n & 1) ? -Yr[16] : Yr[16]);
    int kk = n;
#pragma unroll
    for (int k = 1; k <= 15; ++k) {
      v += 2.f * (Yr[k] * ct[kk] - Yi[k] * st[kk]);
      kk = (kk + n) & 31;
    }
    fo[n] = v * (1.f / 32.f);
  }
}

// -------------------------------------------------------------------------
// Oscillator bank (3-point lerp endpoints + f64 chunk base + f32 Kahan).
// -------------------------------------------------------------------------
static __device__ __forceinline__ int clamp64(int i) { return i < 0 ? 0 : (i > 63 ? 63 : i); }

__global__ void __launch_bounds__(256) osc_phase(
    const float* __restrict__ fsm, double* __restrict__ phaseBase)
{
  const int o = blockIdx.x, b = blockIdx.y;
  const float* frow = fsm + (size_t)(b * 128 + o) * 64;
  const int c = threadIdx.x;

  const float ic0 = ((float)(c * 64) - 127.5f) * (1.0f / 256.0f);
  const int ilo = (int)floorf(ic0);
  float f0 = frow[clamp64(ilo)], f1 = frow[clamp64(ilo + 1)], f2 = frow[clamp64(ilo + 2)];

  double local = 0.0;
#pragma unroll 8
  for (int j = 0; j < 64; ++j) {
    float ic = ic0 + (float)j * (1.0f / 256.0f);
    float fl = floorf(ic);
    float w  = ic - fl;
    bool hi = ((int)fl) > ilo;
    float fa = hi ? f1 : f0;
    float fb = hi ? f2 : f1;
    float f = fa * (1.f - w) + fb * w;
    f = fminf(fmaxf(f, 20.f), 11025.f);
    local += (double)f;
  }
  local *= (1.0 / 22050.0);

  __shared__ double ps[256];
  ps[c] = local;
  __syncthreads();
  for (int off = 1; off < 256; off <<= 1) {
    double v = (c >= off) ? ps[c - off] : 0.0;
    __syncthreads();
    ps[c] += v;
    __syncthreads();
  }
  phaseBase[(size_t)(b * 128 + o) * 256 + c] = ps[c] - local;
}

__global__ void __launch_bounds__(128) osc_sum(
    const float* __restrict__ fsm, const float* __restrict__ lsm,
    const double* __restrict__ phaseBase, const float* __restrict__ filt,
    float* __restrict__ out)
{
  const int c = blockIdx.x, b = blockIdx.y;
  const int tid = threadIdx.x;
  __shared__ float contrib[128][65];
  __shared__ float part[2][64];
  const int o = tid;
  const float* frow = fsm + (size_t)(b * 128 + o) * 64;
  const float* arow = lsm + (size_t)(b * 128 + o) * 64;

  double pb = phaseBase[(size_t)(b * 128 + o) * 256 + c];
  float fb0 = (float)(pb - floor(pb));

  const float ic0 = ((float)(c * 64) - 127.5f) * (1.0f / 256.0f);
  const int ilo = (int)floorf(ic0);
  float f0 = frow[clamp64(ilo)], f1 = frow[clamp64(ilo + 1)], f2 = frow[clamp64(ilo + 2)];
  float a0 = arow[clamp64(ilo)], a1 = arow[clamp64(ilo + 1)], a2 = arow[clamp64(ilo + 2)];

  float rel = 0.f, comp = 0.f;
#pragma unroll 8
  for (int j = 0; j < 64; ++j) {
    float ic = ic0 + (float)j * (1.0f / 256.0f);
    float fl = floorf(ic);
    float w  = ic - fl;
    bool hi = ((int)fl) > ilo;
    float fa = hi ? f1 : f0;
    float fb = hi ? f2 : f1;
    float f = fa * (1.f - w) + fb * w;
    f = fminf(fmaxf(f, 20.f), 11025.f);
    float y = f * (1.0f / 22050.0f) - comp;
    float t = rel + y;
    comp = (t - rel) - y;
    rel = t;
    float tot = fb0 + rel;
    float frac = tot - floorf(tot);
    float s = sinpif(2.f * frac);
    float aa = hi ? a1 : a0;
    float ab = hi ? a2 : a1;
    float am = aa * (1.f - w) + ab * w;
    contrib[o][j] = s * am;
  }
  __syncthreads();
  int half = tid >> 6, tl = tid & 63;
  float sum = 0.f;
  for (int oo = 0; oo < 64; ++oo) sum += contrib[half * 64 + oo][tl];
  part[half][tl] = sum;
  __syncthreads();
  if (tid < 64) {
    int t = c * 64 + tid;
    float v = part[0][tid] + part[1][tid];
    int i0 = t >> 4, r = t & 15;
    v += filt[((size_t)(b << 10) + i0) * 32 + r];
    if (i0 > 0) v += filt[((size_t)(b << 10) + i0 - 1) * 32 + 16 + r];
    out[(size_t)b * 16384 + t] = v;
  }
}

// -------------------------------------------------------------------------
extern "C" void kernel_launch(void* const* d_in, const int* in_sizes, int n_in,
                              void* d_out, int out_size, void* d_ws, size_t ws_size,
                              hipStream_t stream)
{
  (void)in_sizes; (void)n_in; (void)out_size; (void)ws_size;

  const float* x     = (const float*)d_in[0];
  const float* noise = (const float*)d_in[1];
  const float* mw0 = (const float*)d_in[2];  const float* mb0 = (const float*)d_in[3];
  const float* mw1 = (const float*)d_in[4];  const float* mb1 = (const float*)d_in[5];
  const float* mw2 = (const float*)d_in[6];  const float* mb2 = (const float*)d_in[7];
  const float* mw3 = (const float*)d_in[8];  const float* mb3 = (const float*)d_in[9];
  const float* fw  = (const float*)d_in[10]; const float* fb  = (const float*)d_in[11];
  const float* gw0 = (const float*)d_in[12]; const float* gb0 = (const float*)d_in[13];
  const float* gw1 = (const float*)d_in[14]; const float* gb1 = (const float*)d_in[15];
  const float* gw2 = (const float*)d_in[16]; const float* gb2 = (const float*)d_in[17];
  const float* gw3 = (const float*)d_in[18]; const float* gb3 = (const float*)d_in[19];
  const float* lw  = (const float*)d_in[20]; const float* lb  = (const float*)d_in[21];
  const float* nw0 = (const float*)d_in[22]; const float* nb0 = (const float*)d_in[23];
  const float* nw1 = (const float*)d_in[24]; const float* nb1 = (const float*)d_in[25];
  const float* nw2 = (const float*)d_in[26]; const float* nb2 = (const float*)d_in[27];
  const float* nw3 = (const float*)d_in[28]; const float* nb3 = (const float*)d_in[29];
  const float* nlw = (const float*)d_in[30]; const float* nlb = (const float*)d_in[31];

  // ---- workspace (BYTE offsets; high-water 60,555,264 B) ----
  // Region liveness verified against launch order:
  //  phase A: mP[0,16.5M) gP[16.5,33.0M) hm0[33.03,36.18M) hm1[36.18,39.32M)
  //           hg0[39.32,42.47M) hg1[42.47,45.61M) xm3[58.72,59.51M)
  //           fsm[59.51,60.03M) lsm[60.03,60.56M)
  //  phase N (fold_all runs after conv_path#5; mP/gP/hm*/hg* dead):
  //   E4[0,8.39M)  E3[33.55,41.94M)  E2[41.94,50.33M)  E1[50.33,52.43M)
  //   l1out[52.43,56.62M)  l2out[25.17,33.55M)  l3out[8.39,25.17M)
  //   l4out[25.17,58.72M)  (written after l2out/E3/E2/E1/l1out die)
  //  tail: nl[0,1.11M) filt[1.11,3.21M) phaseBase[4.19,8.39M)
  char* W8 = (char*)d_ws;
  short* mP  = (short*)(W8 + 0);
  short* gP  = (short*)(W8 + 16515072);
  short* hm0 = (short*)(W8 + 33030144);
  short* hm1 = (short*)(W8 + 36175872);
  short* hg0 = (short*)(W8 + 39321600);
  short* hg1 = (short*)(W8 + 42467328);
  short* xm3 = (short*)(W8 + 58720256);
  float* fsm = (float*)(W8 + 59506688);
  float* lsm = (float*)(W8 + 60030976);

  short* E4  = (short*)(W8 + 0);           // 8,388,608 B (4,194,304 shorts)
  short* E3  = (short*)(W8 + 33554432);    // 8,388,608 B
  short* E2  = (short*)(W8 + 41943040);    // 8,388,608 B
  short* E1  = (short*)(W8 + 50331648);    // 2,097,152 B
  short* l1out = (short*)(W8 + 52428800);  // 4,194,304 B
  short* l2out = (short*)(W8 + 25165824);  // 8,388,608 B
  short* l3out = (short*)(W8 + 8388608);   // 16,777,216 B
  float* l4out = (float*)(W8 + 25165824);  // 33,554,432 B

  float* nl   = (float*)(W8 + 0);          // 1,114,112 B
  float* filt = (float*)(W8 + 1114112);    // 2,097,152 B
  double* phaseBase = (double*)(W8 + 4194304);  // 4,194,304 B

  float* out = (float*)d_out;

  const int PS_X = 131072;   // xm3 plane stride (shorts)
  const int PS_H = 524288;   // m/g act plane stride (shorts)

  // ---- prep ----
  prep_acts<<<512, 256, 0, stream>>>(x, xm3);
  prep_panels<<<7168, 256, 0, stream>>>(mw0, mw1, mw2, mw3, fw,
                                        gw0, gw1, gw2, gw3, lw, mP, gP);

  // ---- m/g paths ----
  conv_path<<<256, 256, 0, stream>>>(xm3, xm3, mP + 0, gP + 0, mb0, gb0,
      nullptr, nullptr, hm0, hg0, 128, 512, PS_X, PS_H, ACT_LRELU, ACT_LRELU);
  conv_path<<<256, 256, 0, stream>>>(hm0, hg0, mP + 589824, gP + 589824, mb1, gb1,
      nullptr, nullptr, hm1, hg1, 512, 512, PS_H, PS_H, ACT_LRELU, ACT_LRELU);
  conv_path<<<256, 256, 0, stream>>>(hm1, hg1, mP + 2949120, gP + 2949120, mb2, gb2,
      nullptr, nullptr, hm0, hg0, 512, 512, PS_H, PS_H, ACT_LRELU, ACT_LRELU);
  conv_path<<<256, 256, 0, stream>>>(hm0, hg0, mP + 5308416, gP + 5308416, mb3, gb3,
      nullptr, nullptr, hm1, hg1, 512, 512, PS_H, PS_H, ACT_LRELU, ACT_LRELU);
  conv_path<<<64, 256, 0, stream>>>(hm1, hg1, mP + 7667712, gP + 7667712, fb, lb,
      fsm, lsm, nullptr, nullptr, 512, 128, PS_H, 0, ACT_SIGMAP, ACT_SQUARE);

  // ---- noise path ----
  fold_all<<<3328, 256, 0, stream>>>(nw0, nw1, nw2, nw3, E1, E2, E3, E4);
  conv_noise<1, 64, 128, false><<<256, 256, 0, stream>>>(xm3, E1, nb0, nullptr, l1out,
      64, PS_X, 1048576);
  conv_noise<2, 64, 512, false><<<256, 256, 0, stream>>>(l1out, E2, nb1, nullptr, l2out,
      128, 1048576, 2097152);
  conv_noise<2, 128, 512, false><<<256, 256, 0, stream>>>(l2out, E3, nb2, nullptr, l3out,
      256, 2097152, 4194304);
  conv_noise<2, 128, 512, true><<<512, 256, 0, stream>>>(l3out, E4, nb3, l4out, nullptr,
      512, 4194304, 0);

  conv_nl<<<dim3(16, 16), 256, 0, stream>>>(l4out, nlw, nlb, nl);

  // ---- filtered noise frames ----
  noise_filter<<<256, 64, 0, stream>>>(noise, nl, filt);

  // ---- oscillator bank + final sum ----
  osc_phase<<<dim3(128, 16), 256, 0, stream>>>(fsm, phaseBase);
  osc_sum<<<dim3(256, 16), 128, 0, stream>>>(fsm, lsm, phaseBase, filt, out);
}

// Round 8
// 553.168 us; speedup vs baseline: 6.1844x; 1.0794x over previous
//
#include <hip/hip_runtime.h>
#include <math.h>

#define ACT_LRELU  0
#define ACT_SIGMAP 1
#define ACT_SQUARE 2

typedef __attribute__((ext_vector_type(8))) short v8s;
typedef __attribute__((ext_vector_type(4))) short v4s;
typedef __attribute__((ext_vector_type(16))) float f32x16;

static __device__ __forceinline__ float lrelu(float x) { return x >= 0.f ? x : 0.2f * x; }

static __device__ __forceinline__ short bf16rne(float x) {
  unsigned u = __float_as_uint(x);
  unsigned r = (u + 0x7FFFu + ((u >> 16) & 1u)) >> 16;
  return (short)r;
}
static __device__ __forceinline__ float bf16tof(short h) {
  return __uint_as_float(((unsigned)(unsigned short)h) << 16);
}
static __device__ __forceinline__ void split3(float v, short& h, short& l, short& q) {
  h = bf16rne(v); float r1 = v - bf16tof(h);
  l = bf16rne(r1); float r2 = r1 - bf16tof(l);
  q = bf16rne(r2);
}

// -------------------------------------------------------------------------
// prep_acts: x[b][128][64] -> xm3[pl][b][t][ci], 3 bf16 planes (~exact fp32)
// -------------------------------------------------------------------------
__global__ void __launch_bounds__(256) prep_acts(
    const float* __restrict__ x, short* __restrict__ xm3)
{
  int e = blockIdx.x * 256 + threadIdx.x;
  if (e >= 131072) return;
  int b = e >> 13, rem = e & 8191, t = rem >> 7, ci = rem & 127;
  float v = x[((size_t)(b * 128) + ci) * 64 + t];
  short h, l, q; split3(v, h, l, q);
  size_t o = ((size_t)(b * 64) + t) * 128 + ci;
  xm3[0 * 131072 + o] = h;
  xm3[1 * 131072 + o] = l;
  xm3[2 * 131072 + o] = q;
}

// -------------------------------------------------------------------------
// prep_panels: all 5 m/g layers, both paths. W[Cout][Cin][3] ->
// P[pl][co][tap*Cin+ci] (3 bf16 planes, tap-major K).
// -------------------------------------------------------------------------
__global__ void __launch_bounds__(256) prep_panels(
    const float* mw0, const float* mw1, const float* mw2, const float* mw3, const float* fw,
    const float* gw0, const float* gw1, const float* gw2, const float* gw3, const float* lw,
    short* __restrict__ mP, short* __restrict__ gP)
{
  int i = blockIdx.x * 256 + threadIdx.x;
  const int PER_PATH = 917504;
  if (i >= 2 * PER_PATH) return;
  int path = i >= PER_PATH ? 1 : 0;
  int r = i - path * PER_PATH;
  int layer, Cin, Cout; size_t poff;
  if (r < 65536)       { layer = 0;               Cin = 128; Cout = 512; poff = 0; }
  else if (r < 327680) { layer = 1; r -= 65536;   Cin = 512; Cout = 512; poff = 589824; }
  else if (r < 589824) { layer = 2; r -= 327680;  Cin = 512; Cout = 512; poff = 2949120; }
  else if (r < 851968) { layer = 3; r -= 589824;  Cin = 512; Cout = 512; poff = 5308416; }
  else                 { layer = 4; r -= 851968;  Cin = 512; Cout = 128; poff = 7667712; }
  const float* Wm[5] = {mw0, mw1, mw2, mw3, fw};
  const float* Wg[5] = {gw0, gw1, gw2, gw3, lw};
  const float* W = path ? Wg[layer] : Wm[layer];
  short* P = (path ? gP : mP) + poff;
  int co = r / Cin, ci = r - co * Cin;
  const int K3 = 3 * Cin;
  const float* wp = W + (size_t)(co * Cin + ci) * 3;
#pragma unroll
  for (int tap = 0; tap < 3; ++tap) {
    short h, l, q; split3(wp[tap], h, l, q);
    size_t base = (size_t)co * K3 + tap * Cin + ci;
    P[(size_t)0 * Cout * K3 + base] = h;
    P[(size_t)1 * Cout * K3 + base] = l;
    P[(size_t)2 * Cout * K3 + base] = q;
  }
}

// -------------------------------------------------------------------------
// m/g path conv: 3-plane split-bf16 MFMA GEMM, 32x32x16, ~fp32 precision,
// T14 async staging.
// -------------------------------------------------------------------------
__global__ void __launch_bounds__(256, 2) conv_path(
    const short* __restrict__ actM, const short* __restrict__ actG,
    const short* __restrict__ Pm, const short* __restrict__ Pg,
    const float* __restrict__ BsM, const float* __restrict__ BsG,
    float* __restrict__ foutM, float* __restrict__ foutG,
    short* __restrict__ soutM, short* __restrict__ soutG,
    int Cin, int Cout, int psIn, int psOut, int actMk, int actGk)
{
  const int mtiles = Cout >> 6;
  const int nblk = 2 * mtiles * 16;
  const int Q = nblk >> 3;
  int d = blockIdx.x;
  int idx = (d & 7) * Q + (d >> 3);
  int mt = idx % mtiles;
  int tmp = idx / mtiles;
  int nt = tmp & 15;
  int path = tmp >> 4;

  const short* act = path ? actG : actM;
  const short* P   = path ? Pg : Pm;
  const float* Bs  = path ? BsG : BsM;
  float* fout      = path ? foutG : foutM;
  short* sout      = path ? soutG : soutM;
  const int actk   = path ? actGk : actMk;

  const int K3 = 3 * Cin;
  const int co0 = mt * 64;
  const int n0  = nt * 64;
  const int nci = Cin >> 6;
  const int NT  = 3 * nci;

  const int tid = threadIdx.x;
  const int w = tid >> 6, wm = w & 1, wn = w >> 1;
  const int l = tid & 63;

  __shared__ __align__(16) short Al[3][64 * 72];
  __shared__ __align__(16) short Bl[3][64 * 72];
  __shared__ float bandS[2][128];

  if (actk == ACT_SIGMAP && tid < 128) {
    double lg = log(551.25);
    double stop  = 20.0 * exp(lg * (double)tid / 127.0);
    double start = (tid == 0) ? 0.0 : 20.0 * exp(lg * (double)(tid - 1) / 127.0);
    bandS[0][tid] = (float)start;
    bandS[1][tid] = (float)(stop - start);
  }

  f32x16 acc = {};
  v8s rA[3][2], rB[3][2];

  auto LOADA = [&](int t) {
    int tap = t / nci, ci0 = (t % nci) << 6;
#pragma unroll
    for (int pl = 0; pl < 3; ++pl)
#pragma unroll
      for (int it = 0; it < 2; ++it) {
        int e = it * 256 + tid;
        int row = e >> 3, c8 = e & 7;
        rA[pl][it] = *(const v8s*)&P[(size_t)pl * Cout * K3 + (size_t)(co0 + row) * K3
                                     + tap * Cin + ci0 + c8 * 8];
      }
  };
  auto LOADB = [&](int t) {
    int tap = t / nci, ci0 = (t % nci) << 6;
#pragma unroll
    for (int pl = 0; pl < 3; ++pl)
#pragma unroll
      for (int it = 0; it < 2; ++it) {
        int e = it * 256 + tid;
        int n = e >> 3, c8 = e & 7;
        int gn = n0 + n, bb = gn >> 6, trow = (gn & 63) + tap - 1;
        v8s vv = {};
        if (trow >= 0 && trow < 64)
          vv = *(const v8s*)&act[(size_t)pl * psIn + ((size_t)(bb * 64 + trow)) * Cin
                                 + ci0 + c8 * 8];
        rB[pl][it] = vv;
      }
  };
  auto WRITE = [&]() {
#pragma unroll
    for (int pl = 0; pl < 3; ++pl)
#pragma unroll
      for (int it = 0; it < 2; ++it) {
        int e = it * 256 + tid;
        int row = e >> 3, c8 = e & 7;
        *(v8s*)&Al[pl][row * 72 + c8 * 8] = rA[pl][it];
        *(v8s*)&Bl[pl][row * 72 + c8 * 8] = rB[pl][it];
      }
  };

  LOADA(0); LOADB(0);
  WRITE();
  __syncthreads();

  for (int t = 0; t < NT; ++t) {
    if (t + 1 < NT) { LOADA(t + 1); LOADB(t + 1); }
    const int abase = (wm * 32 + (l & 31)) * 72 + (l >> 5) * 8;
    const int bbase = (wn * 32 + (l & 31)) * 72 + (l >> 5) * 8;
#pragma unroll
    for (int kk = 0; kk < 4; ++kk) {
      v8s a0 = *(const v8s*)&Al[0][abase + kk * 16];
      v8s a1 = *(const v8s*)&Al[1][abase + kk * 16];
      v8s a2 = *(const v8s*)&Al[2][abase + kk * 16];
      v8s b0 = *(const v8s*)&Bl[0][bbase + kk * 16];
      v8s b1 = *(const v8s*)&Bl[1][bbase + kk * 16];
      v8s b2 = *(const v8s*)&Bl[2][bbase + kk * 16];
      acc = __builtin_amdgcn_mfma_f32_32x32x16_bf16(a0, b0, acc, 0, 0, 0);
      acc = __builtin_amdgcn_mfma_f32_32x32x16_bf16(a0, b1, acc, 0, 0, 0);
      acc = __builtin_amdgcn_mfma_f32_32x32x16_bf16(a1, b0, acc, 0, 0, 0);
      acc = __builtin_amdgcn_mfma_f32_32x32x16_bf16(a1, b1, acc, 0, 0, 0);
      acc = __builtin_amdgcn_mfma_f32_32x32x16_bf16(a0, b2, acc, 0, 0, 0);
      acc = __builtin_amdgcn_mfma_f32_32x32x16_bf16(a2, b0, acc, 0, 0, 0);
    }
    __syncthreads();
    if (t + 1 < NT) { WRITE(); __syncthreads(); }
  }

  // epilogue: C/D layout col=lane&31, row=(r&3)+8*(r>>2)+4*(lane>>5)
  const int ncol = wn * 32 + (l & 31);
  const int gn = n0 + ncol, bb = gn >> 6, t = gn & 63;
  const int hi4 = 4 * (l >> 5);
#pragma unroll
  for (int q4 = 0; q4 < 4; ++q4) {
    int co = co0 + wm * 32 + q4 * 8 + hi4;
    float4 bia = *(const float4*)&Bs[co];
    const float* bp = &bia.x;
    float z[4];
#pragma unroll
    for (int j = 0; j < 4; ++j) z[j] = acc[q4 * 4 + j] + bp[j];
    if (actk == ACT_LRELU) {
      v4s h4, l4, q4v;
#pragma unroll
      for (int j = 0; j < 4; ++j) {
        float zz = lrelu(z[j]);
        short h, lo, qq; split3(zz, h, lo, qq);
        h4[j] = h; l4[j] = lo; q4v[j] = qq;
      }
      size_t o = ((size_t)(bb * 64) + t) * Cout + co;
      *(v4s*)&sout[0 * (size_t)psOut + o] = h4;
      *(v4s*)&sout[1 * (size_t)psOut + o] = l4;
      *(v4s*)&sout[2 * (size_t)psOut + o] = q4v;
    } else if (actk == ACT_SIGMAP) {
#pragma unroll
      for (int j = 0; j < 4; ++j) {
        float f = bandS[0][co + j] + bandS[1][co + j] / (1.f + expf(-z[j]));
        fout[((size_t)(bb * 128) + co + j) * 64 + t] = f;
      }
    } else {
#pragma unroll
      for (int j = 0; j < 4; ++j)
        fout[((size_t)(bb * 128) + co + j) * 64 + t] = z[j] * z[j];
    }
  }
}

// -------------------------------------------------------------------------
// fold_all: 4 noise layers (k=7+nearest-x2 -> 4-tap parity, hi/lo bf16,
// tap-major) + nl panel (17->32 padded, k=3, hi/lo, tap-major K=1536).
// -------------------------------------------------------------------------
__global__ void __launch_bounds__(256) fold_all(
    const float* __restrict__ nw0, const float* __restrict__ nw1,
    const float* __restrict__ nw2, const float* __restrict__ nw3,
    const float* __restrict__ nlw,
    short* __restrict__ E1, short* __restrict__ E2,
    short* __restrict__ E3, short* __restrict__ E4,
    short* __restrict__ Pnl)
{
  int i = blockIdx.x * 256 + threadIdx.x;
  if (i >= 851968) {
    if (i >= 868352) return;
    int idx = i - 851968;             // [0, 32*512)
    int co = idx >> 9, ci = idx & 511;
#pragma unroll
    for (int tap = 0; tap < 3; ++tap) {
      float v = (co < 17) ? nlw[((size_t)(co * 512 + ci)) * 3 + tap] : 0.f;
      short h = bf16rne(v);
      short lo = bf16rne(v - bf16tof(h));
      Pnl[(size_t)(0 * 32 + co) * 1536 + tap * 512 + ci] = h;
      Pnl[(size_t)(1 * 32 + co) * 1536 + tap * 512 + ci] = lo;
    }
    return;
  }
  const float* W; short* Ag; int Cin; int idx;
  if (i < 65536)        { W = nw0; Ag = E1; Cin = 128; idx = i; }
  else if (i < 327680)  { W = nw1; Ag = E2; Cin = 512; idx = i - 65536; }
  else if (i < 589824)  { W = nw2; Ag = E3; Cin = 512; idx = i - 327680; }
  else                  { W = nw3; Ag = E4; Cin = 512; idx = i - 589824; }
  int co = idx / Cin, ci = idx - co * Cin;
  const float* wp = W + (size_t)idx * 7;
  float f[2][4] = {{wp[0],         wp[1] + wp[2], wp[3] + wp[4], wp[5] + wp[6]},
                   {wp[0] + wp[1], wp[2] + wp[3], wp[4] + wp[5], wp[6]}};
  const int K = Cin * 4;
#pragma unroll
  for (int par = 0; par < 2; ++par)
#pragma unroll
    for (int q = 0; q < 4; ++q) {
      float v = f[par][q];
      short h = bf16rne(v);
      short lo = bf16rne(v - bf16tof(h));
      Ag[((size_t)((par * 2 + 0) * 512 + co)) * K + q * Cin + ci] = h;
      Ag[((size_t)((par * 2 + 1) * 512 + co)) * K + q * Cin + ci] = lo;
    }
}

// -------------------------------------------------------------------------
// Noise conv: 2-plane split-bf16 MFMA GEMM (hh,hl,lh), 32x32x16, T14 async.
// Always writes 2-plane bf16 [pl][b][t][512] for the next consumer.
// -------------------------------------------------------------------------
template<int MF, int BNS, int CIN>
__global__ void __launch_bounds__(256, 2) conv_noise(
    const short* __restrict__ actIn, const short* __restrict__ Ag,
    const float* __restrict__ Bs, short* __restrict__ actOut,
    int Sin, int psIn, int psOut)
{
  constexpr int NF   = BNS / 64;
  constexpr int BM   = MF * 64;
  constexpr int AITS = BM / 32;
  constexpr int BITS = BNS / 32;
  constexpr int K    = CIN * 4;
  constexpr int nci  = CIN / 64;
  constexpr int NT   = 4 * nci;
  const int mtiles = 512 / BM;
  const int stiles = Sin / BNS;
  const int nblk = mtiles * 2 * 16 * stiles;
  const int Q = nblk >> 3;
  int d = blockIdx.x;
  int idx = (d & 7) * Q + (d >> 3);
  int mt = idx % mtiles;
  int t1 = idx / mtiles;
  int par = t1 & 1;
  int rest = t1 >> 1;
  int st = rest % stiles;
  int b = rest / stiles;

  const int co0 = mt * BM;
  const int s0 = st * BNS;
  const int soff = par ? -1 : -2;

  const int tid = threadIdx.x;
  const int w = tid >> 6, wm = w & 1, wn = w >> 1;
  const int l = tid & 63;

  __shared__ __align__(16) short Al[2][BM * 72];
  __shared__ __align__(16) short Bl[2][BNS * 72];

  f32x16 acc[MF][NF] = {};
  v8s rA[2][AITS], rB[2][BITS];

  auto LOADA = [&](int t) {
    int q = t / nci, ci0 = (t % nci) << 6;
#pragma unroll
    for (int pl = 0; pl < 2; ++pl)
#pragma unroll
      for (int it = 0; it < AITS; ++it) {
        int e = it * 256 + tid;
        int row = e >> 3, c8 = e & 7;
        rA[pl][it] = *(const v8s*)&Ag[((size_t)((par * 2 + pl) * 512 + co0 + row)) * K
                                      + q * CIN + ci0 + c8 * 8];
      }
  };
  auto LOADB = [&](int t) {
    int q = t / nci, ci0 = (t % nci) << 6;
#pragma unroll
    for (int pl = 0; pl < 2; ++pl)
#pragma unroll
      for (int it = 0; it < BITS; ++it) {
        int e = it * 256 + tid;
        int n = e >> 3, c8 = e & 7;
        int srow = s0 + n + q + soff;
        v8s vv = {};
        if (srow >= 0 && srow < Sin)
          vv = *(const v8s*)&actIn[(size_t)pl * psIn + ((size_t)(b * Sin + srow)) * CIN
                                   + ci0 + c8 * 8];
        rB[pl][it] = vv;
      }
  };
  auto WRITE = [&]() {
#pragma unroll
    for (int pl = 0; pl < 2; ++pl) {
#pragma unroll
      for (int it = 0; it < AITS; ++it) {
        int e = it * 256 + tid;
        *(v8s*)&Al[pl][(e >> 3) * 72 + (e & 7) * 8] = rA[pl][it];
      }
#pragma unroll
      for (int it = 0; it < BITS; ++it) {
        int e = it * 256 + tid;
        *(v8s*)&Bl[pl][(e >> 3) * 72 + (e & 7) * 8] = rB[pl][it];
      }
    }
  };

  LOADA(0); LOADB(0);
  WRITE();
  __syncthreads();

  for (int t = 0; t < NT; ++t) {
    if (t + 1 < NT) { LOADA(t + 1); LOADB(t + 1); }
    const int lr = l & 31, lh = (l >> 5) * 8;
#pragma unroll
    for (int kk = 0; kk < 4; ++kk) {
      v8s ah[MF], al[MF], bh[NF], bl[NF];
#pragma unroll
      for (int fm = 0; fm < MF; ++fm) {
        int ab = (wm * (MF * 32) + fm * 32 + lr) * 72 + kk * 16 + lh;
        ah[fm] = *(const v8s*)&Al[0][ab];
        al[fm] = *(const v8s*)&Al[1][ab];
      }
#pragma unroll
      for (int fn = 0; fn < NF; ++fn) {
        int bb = (wn * (BNS / 2) + fn * 32 + lr) * 72 + kk * 16 + lh;
        bh[fn] = *(const v8s*)&Bl[0][bb];
        bl[fn] = *(const v8s*)&Bl[1][bb];
      }
#pragma unroll
      for (int fm = 0; fm < MF; ++fm)
#pragma unroll
        for (int fn = 0; fn < NF; ++fn) {
          acc[fm][fn] = __builtin_amdgcn_mfma_f32_32x32x16_bf16(ah[fm], bh[fn], acc[fm][fn], 0, 0, 0);
          acc[fm][fn] = __builtin_amdgcn_mfma_f32_32x32x16_bf16(ah[fm], bl[fn], acc[fm][fn], 0, 0, 0);
          acc[fm][fn] = __builtin_amdgcn_mfma_f32_32x32x16_bf16(al[fm], bh[fn], acc[fm][fn], 0, 0, 0);
        }
    }
    __syncthreads();
    if (t + 1 < NT) { WRITE(); __syncthreads(); }
  }

  // epilogue: always 2-plane bf16 [pl][b][t=2s+par][512]
  const int hi4 = 4 * (l >> 5);
  const int T2 = 2 * Sin;
#pragma unroll
  for (int fm = 0; fm < MF; ++fm)
#pragma unroll
    for (int q4 = 0; q4 < 4; ++q4) {
      int co = co0 + wm * (MF * 32) + fm * 32 + q4 * 8 + hi4;
      float4 bia = *(const float4*)&Bs[co];
      const float* bp = &bia.x;
#pragma unroll
      for (int fn = 0; fn < NF; ++fn) {
        int s_l = wn * (BNS / 2) + fn * 32 + (l & 31);
        int t = 2 * (s0 + s_l) + par;
        v4s h4, l4;
#pragma unroll
        for (int j = 0; j < 4; ++j) {
          float z = lrelu(acc[fm][fn][q4 * 4 + j] + bp[j]);
          short h = bf16rne(z);
          h4[j] = h;
          l4[j] = bf16rne(z - bf16tof(h));
        }
        size_t o = ((size_t)(b * T2) + t) * 512 + co;
        *(v4s*)&actOut[0 * (size_t)psOut + o] = h4;
        *(v4s*)&actOut[1 * (size_t)psOut + o] = l4;
      }
    }
}

// -------------------------------------------------------------------------
// conv_nl as split-bf16 MFMA GEMM: M=32 (17 padded), K=3*512 via shifted-row
// LDS taps, N=16x1024. BN=64, 2 waves, grid 256. Output squared.
// -------------------------------------------------------------------------
#define NL_PS4 8388608   // l4act plane stride (shorts)

__global__ void __launch_bounds__(128) conv_nl_mfma(
    const short* __restrict__ act, const short* __restrict__ Pnl,
    const float* __restrict__ Bs, float* __restrict__ outNl)
{
  const int bid = blockIdx.x;
  const int b = bid >> 4, t0 = (bid & 15) << 6;
  const int tid = threadIdx.x;
  const int w = tid >> 6;        // 0..1
  const int l = tid & 63;

  __shared__ __align__(16) short Al[2 * 3 * 32 * 72];
  __shared__ __align__(16) short Bl[2 * 66 * 72];

  f32x16 acc = {};

  for (int ci0 = 0; ci0 < 512; ci0 += 64) {
    // stage A: 2pl x 3tap x 32co x 8 (v8s) = 1536
    for (int e = tid; e < 1536; e += 128) {
      int c8 = e & 7, row = e >> 3;          // row = (pl*3+tap)*32+co
      int pl = row >= 96;
      int r2 = row - pl * 96;
      int tap = r2 >> 5, co = r2 & 31;
      v8s vv = *(const v8s*)&Pnl[(size_t)(pl * 32 + co) * 1536 + tap * 512 + ci0 + c8 * 8];
      *(v8s*)&Al[row * 72 + c8 * 8] = vv;
    }
    // stage B: 2pl x 66 rows (t0-1 .. t0+64) x 8 = 1056
    for (int e = tid; e < 1056; e += 128) {
      int c8 = e & 7, r = (e >> 3) % 66, pl = (e >> 3) / 66;
      int t = t0 + r - 1;
      v8s vv = {};
      if (t >= 0 && t < 1024)
        vv = *(const v8s*)&act[(size_t)pl * NL_PS4 + ((size_t)(b << 10) + t) * 512 + ci0 + c8 * 8];
      *(v8s*)&Bl[(pl * 66 + r) * 72 + c8 * 8] = vv;
    }
    __syncthreads();
    const int lr = l & 31, lh = (l >> 5) * 8;
#pragma unroll
    for (int kk = 0; kk < 4; ++kk)
#pragma unroll
      for (int tap = 0; tap < 3; ++tap) {
        v8s a_h = *(const v8s*)&Al[((0 * 3 + tap) * 32 + lr) * 72 + kk * 16 + lh];
        v8s a_l = *(const v8s*)&Al[((1 * 3 + tap) * 32 + lr) * 72 + kk * 16 + lh];
        int brow = w * 32 + lr + tap;
        v8s b_h = *(const v8s*)&Bl[(0 * 66 + brow) * 72 + kk * 16 + lh];
        v8s b_l = *(const v8s*)&Bl[(1 * 66 + brow) * 72 + kk * 16 + lh];
        acc = __builtin_amdgcn_mfma_f32_32x32x16_bf16(a_h, b_h, acc, 0, 0, 0);
        acc = __builtin_amdgcn_mfma_f32_32x32x16_bf16(a_h, b_l, acc, 0, 0, 0);
        acc = __builtin_amdgcn_mfma_f32_32x32x16_bf16(a_l, b_h, acc, 0, 0, 0);
      }
    __syncthreads();
  }

  const int t = t0 + w * 32 + (l & 31);
  const int hi4 = 4 * (l >> 5);
#pragma unroll
  for (int q4 = 0; q4 < 4; ++q4) {
#pragma unroll
    for (int j = 0; j < 4; ++j) {
      int co = q4 * 8 + hi4 + j;
      if (co < 17) {
        float z = acc[q4 * 4 + j] + Bs[co];
        outNl[((size_t)(b * 17) + co) * 1024 + t] = z * z;
      }
    }
  }
}

// -------------------------------------------------------------------------
// Noise bank: per 32-sample frame, 17-bin real DFT * mags, inverse, store.
// -------------------------------------------------------------------------
__global__ void __launch_bounds__(64) noise_filter(
    const float* __restrict__ noise, const float* __restrict__ mags,
    float* __restrict__ filt)
{
  __shared__ float ct[32], st[32];
  int tid = threadIdx.x;
  if (tid < 32) {
    double a = (double)tid * (3.14159265358979323846 / 16.0);
    ct[tid] = (float)cos(a);
    st[tid] = (float)sin(a);
  }
  __syncthreads();

  int fidx = blockIdx.x * 64 + tid;
  int b = fidx >> 10, i = fidx & 1023;

  float xv[32];
#pragma unroll
  for (int n = 0; n < 32; ++n) {
    int idx = i * 16 + n;
    xv[n] = (idx < 16384) ? noise[(size_t)b * 16384 + idx] : 0.f;
  }

  float Yr[17], Yi[17];
#pragma unroll
  for (int k = 0; k <= 16; ++k) {
    float xr = 0.f, xi = 0.f;
    int kk = 0;
#pragma unroll
    for (int n = 0; n < 32; ++n) {
      xr += xv[n] * ct[kk];
      xi -= xv[n] * st[kk];
      kk = (kk + k) & 31;
    }
    float m = mags[((size_t)b * 17 + k) * 1024 + i];
    Yr[k] = xr * m;
    Yi[k] = xi * m;
  }

  float* fo = filt + ((size_t)b * 1024 + i) * 32;
#pragma unroll
  for (int n = 0; n < 32; ++n) {
    float v = Yr[0] + ((n & 1) ? -Yr[16] : Yr[16]);
    int kk = n;
#pragma unroll
    for (int k = 1; k <= 15; ++k) {
      v += 2.f * (Yr[k] * ct[kk] - Yi[k] * st[kk]);
      kk = (kk + n) & 31;
    }
    fo[n] = v * (1.f / 32.f);
  }
}

// -------------------------------------------------------------------------
// Oscillator bank (3-point lerp endpoints + f64 chunk base + f32 Kahan).
// -------------------------------------------------------------------------
static __device__ __forceinline__ int clamp64(int i) { return i < 0 ? 0 : (i > 63 ? 63 : i); }

__global__ void __launch_bounds__(256) osc_phase(
    const float* __restrict__ fsm, double* __restrict__ phaseBase)
{
  const int o = blockIdx.x, b = blockIdx.y;
  const float* frow = fsm + (size_t)(b * 128 + o) * 64;
  const int c = threadIdx.x;

  const float ic0 = ((float)(c * 64) - 127.5f) * (1.0f / 256.0f);
  const int ilo = (int)floorf(ic0);
  float f0 = frow[clamp64(ilo)], f1 = frow[clamp64(ilo + 1)], f2 = frow[clamp64(ilo + 2)];

  double local = 0.0;
#pragma unroll 8
  for (int j = 0; j < 64; ++j) {
    float ic = ic0 + (float)j * (1.0f / 256.0f);
    float fl = floorf(ic);
    float w  = ic - fl;
    bool hi = ((int)fl) > ilo;
    float fa = hi ? f1 : f0;
    float fb = hi ? f2 : f1;
    float f = fa * (1.f - w) + fb * w;
    f = fminf(fmaxf(f, 20.f), 11025.f);
    local += (double)f;
  }
  local *= (1.0 / 22050.0);

  __shared__ double ps[256];
  ps[c] = local;
  __syncthreads();
  for (int off = 1; off < 256; off <<= 1) {
    double v = (c >= off) ? ps[c - off] : 0.0;
    __syncthreads();
    ps[c] += v;
    __syncthreads();
  }
  phaseBase[(size_t)(b * 128 + o) * 256 + c] = ps[c] - local;
}

__global__ void __launch_bounds__(128) osc_sum(
    const float* __restrict__ fsm, const float* __restrict__ lsm,
    const double* __restrict__ phaseBase, const float* __restrict__ filt,
    float* __restrict__ out)
{
  const int c = blockIdx.x, b = blockIdx.y;
  const int tid = threadIdx.x;
  __shared__ float contrib[128][65];
  __shared__ float part[2][64];
  const int o = tid;
  const float* frow = fsm + (size_t)(b * 128 + o) * 64;
  const float* arow = lsm + (size_t)(b * 128 + o) * 64;

  double pb = phaseBase[(size_t)(b * 128 + o) * 256 + c];
  float fb0 = (float)(pb - floor(pb));

  const float ic0 = ((float)(c * 64) - 127.5f) * (1.0f / 256.0f);
  const int ilo = (int)floorf(ic0);
  float f0 = frow[clamp64(ilo)], f1 = frow[clamp64(ilo + 1)], f2 = frow[clamp64(ilo + 2)];
  float a0 = arow[clamp64(ilo)], a1 = arow[clamp64(ilo + 1)], a2 = arow[clamp64(ilo + 2)];

  float rel = 0.f, comp = 0.f;
#pragma unroll 8
  for (int j = 0; j < 64; ++j) {
    float ic = ic0 + (float)j * (1.0f / 256.0f);
    float fl = floorf(ic);
    float w  = ic - fl;
    bool hi = ((int)fl) > ilo;
    float fa = hi ? f1 : f0;
    float fb = hi ? f2 : f1;
    float f = fa * (1.f - w) + fb * w;
    f = fminf(fmaxf(f, 20.f), 11025.f);
    float y = f * (1.0f / 22050.0f) - comp;
    float t = rel + y;
    comp = (t - rel) - y;
    rel = t;
    float tot = fb0 + rel;
    float frac = tot - floorf(tot);
    float s = sinpif(2.f * frac);
    float aa = hi ? a1 : a0;
    float ab = hi ? a2 : a1;
    float am = aa * (1.f - w) + ab * w;
    contrib[o][j] = s * am;
  }
  __syncthreads();
  int half = tid >> 6, tl = tid & 63;
  float sum = 0.f;
  for (int oo = 0; oo < 64; ++oo) sum += contrib[half * 64 + oo][tl];
  part[half][tl] = sum;
  __syncthreads();
  if (tid < 64) {
    int t = c * 64 + tid;
    float v = part[0][tid] + part[1][tid];
    int i0 = t >> 4, r = t & 15;
    v += filt[((size_t)(b << 10) + i0) * 32 + r];
    if (i0 > 0) v += filt[((size_t)(b << 10) + i0 - 1) * 32 + 16 + r];
    out[(size_t)b * 16384 + t] = v;
  }
}

// -------------------------------------------------------------------------
extern "C" void kernel_launch(void* const* d_in, const int* in_sizes, int n_in,
                              void* d_out, int out_size, void* d_ws, size_t ws_size,
                              hipStream_t stream)
{
  (void)in_sizes; (void)n_in; (void)out_size; (void)ws_size;

  const float* x     = (const float*)d_in[0];
  const float* noise = (const float*)d_in[1];
  const float* mw0 = (const float*)d_in[2];  const float* mb0 = (const float*)d_in[3];
  const float* mw1 = (const float*)d_in[4];  const float* mb1 = (const float*)d_in[5];
  const float* mw2 = (const float*)d_in[6];  const float* mb2 = (const float*)d_in[7];
  const float* mw3 = (const float*)d_in[8];  const float* mb3 = (const float*)d_in[9];
  const float* fw  = (const float*)d_in[10]; const float* fb  = (const float*)d_in[11];
  const float* gw0 = (const float*)d_in[12]; const float* gb0 = (const float*)d_in[13];
  const float* gw1 = (const float*)d_in[14]; const float* gb1 = (const float*)d_in[15];
  const float* gw2 = (const float*)d_in[16]; const float* gb2 = (const float*)d_in[17];
  const float* gw3 = (const float*)d_in[18]; const float* gb3 = (const float*)d_in[19];
  const float* lw  = (const float*)d_in[20]; const float* lb  = (const float*)d_in[21];
  const float* nw0 = (const float*)d_in[22]; const float* nb0 = (const float*)d_in[23];
  const float* nw1 = (const float*)d_in[24]; const float* nb1 = (const float*)d_in[25];
  const float* nw2 = (const float*)d_in[26]; const float* nb2 = (const float*)d_in[27];
  const float* nw3 = (const float*)d_in[28]; const float* nb3 = (const float*)d_in[29];
  const float* nlw = (const float*)d_in[30]; const float* nlb = (const float*)d_in[31];

  // ---- workspace (BYTE offsets; high-water 60,751,872 B < 63 MB cap) ----
  //  phase A: mP[0,16.5M) gP[16.5,33.0M) hm0/hm1/hg0/hg1[33.03,45.61M)
  //           xm3[58.72,59.51M) fsm[59.51,60.03M) lsm[60.03,60.56M)
  //           Pnl[60.56,60.75M)  (written by fold_all, live whole noise phase)
  //  phase N: E4[0,8.39M) E3[33.55,41.94M) E2[41.94,50.33M) E1[50.33,52.43M)
  //           l1out[52.43,56.62M) l2out[25.17,33.55M) l3out[8.39,25.17M)
  //           l4act[25.17,58.72M) (2-plane bf16, written after l2out/E*/l1out die)
  //  tail: nl[0,1.11M) filt[1.11,3.21M) phaseBase[4.19,8.39M)
  char* W8 = (char*)d_ws;
  short* mP  = (short*)(W8 + 0);
  short* gP  = (short*)(W8 + 16515072);
  short* hm0 = (short*)(W8 + 33030144);
  short* hm1 = (short*)(W8 + 36175872);
  short* hg0 = (short*)(W8 + 39321600);
  short* hg1 = (short*)(W8 + 42467328);
  short* xm3 = (short*)(W8 + 58720256);
  float* fsm = (float*)(W8 + 59506688);
  float* lsm = (float*)(W8 + 60030976);
  short* Pnl = (short*)(W8 + 60555264);    // 196,608 B

  short* E4  = (short*)(W8 + 0);           // 8,388,608 B
  short* E3  = (short*)(W8 + 33554432);    // 8,388,608 B
  short* E2  = (short*)(W8 + 41943040);    // 8,388,608 B
  short* E1  = (short*)(W8 + 50331648);    // 2,097,152 B
  short* l1out = (short*)(W8 + 52428800);  // 4,194,304 B
  short* l2out = (short*)(W8 + 25165824);  // 8,388,608 B
  short* l3out = (short*)(W8 + 8388608);   // 16,777,216 B
  short* l4act = (short*)(W8 + 25165824);  // 33,554,432 B (2 planes x 8,388,608 sh)

  float* nl   = (float*)(W8 + 0);          // 1,114,112 B
  float* filt = (float*)(W8 + 1114112);    // 2,097,152 B
  double* phaseBase = (double*)(W8 + 4194304);  // 4,194,304 B

  float* out = (float*)d_out;

  const int PS_X = 131072;   // xm3 plane stride (shorts)
  const int PS_H = 524288;   // m/g act plane stride (shorts)

  // ---- prep ----
  prep_acts<<<512, 256, 0, stream>>>(x, xm3);
  prep_panels<<<7168, 256, 0, stream>>>(mw0, mw1, mw2, mw3, fw,
                                        gw0, gw1, gw2, gw3, lw, mP, gP);

  // ---- m/g paths ----
  conv_path<<<256, 256, 0, stream>>>(xm3, xm3, mP + 0, gP + 0, mb0, gb0,
      nullptr, nullptr, hm0, hg0, 128, 512, PS_X, PS_H, ACT_LRELU, ACT_LRELU);
  conv_path<<<256, 256, 0, stream>>>(hm0, hg0, mP + 589824, gP + 589824, mb1, gb1,
      nullptr, nullptr, hm1, hg1, 512, 512, PS_H, PS_H, ACT_LRELU, ACT_LRELU);
  conv_path<<<256, 256, 0, stream>>>(hm1, hg1, mP + 2949120, gP + 2949120, mb2, gb2,
      nullptr, nullptr, hm0, hg0, 512, 512, PS_H, PS_H, ACT_LRELU, ACT_LRELU);
  conv_path<<<256, 256, 0, stream>>>(hm0, hg0, mP + 5308416, gP + 5308416, mb3, gb3,
      nullptr, nullptr, hm1, hg1, 512, 512, PS_H, PS_H, ACT_LRELU, ACT_LRELU);
  conv_path<<<64, 256, 0, stream>>>(hm1, hg1, mP + 7667712, gP + 7667712, fb, lb,
      fsm, lsm, nullptr, nullptr, 512, 128, PS_H, 0, ACT_SIGMAP, ACT_SQUARE);

  // ---- noise path ----
  fold_all<<<3392, 256, 0, stream>>>(nw0, nw1, nw2, nw3, nlw, E1, E2, E3, E4, Pnl);
  conv_noise<1, 64, 128><<<256, 256, 0, stream>>>(xm3, E1, nb0, l1out, 64, PS_X, 1048576);
  conv_noise<2, 64, 512><<<256, 256, 0, stream>>>(l1out, E2, nb1, l2out, 128, 1048576, 2097152);
  conv_noise<2, 128, 512><<<256, 256, 0, stream>>>(l2out, E3, nb2, l3out, 256, 2097152, 4194304);
  conv_noise<2, 128, 512><<<512, 256, 0, stream>>>(l3out, E4, nb3, l4act, 512, 4194304, 8388608);

  conv_nl_mfma<<<256, 128, 0, stream>>>(l4act, Pnl, nlb, nl);

  // ---- filtered noise frames ----
  noise_filter<<<256, 64, 0, stream>>>(noise, nl, filt);

  // ---- oscillator bank + final sum ----
  osc_phase<<<dim3(128, 16), 256, 0, stream>>>(fsm, phaseBase);
  osc_sum<<<dim3(256, 16), 128, 0, stream>>>(fsm, lsm, phaseBase, filt, out);
}